// Round 1
// baseline (9362.315 us; speedup 1.0000x reference)
//
#include <hip/hip_runtime.h>
#include <math.h>

#define NTOK   196
#define BATCH  64
#define TOKENS (BATCH*NTOK)   // 12544
#define DIMD   1024
#define PD     768
#define HEADS  8
#define HD     128
#define DEPTH  6
#define LN_EPS 1e-5f

// ---------------- patchify + LN1 (dim 768) ----------------
__global__ __launch_bounds__(256) void patchify_ln(
    const float* __restrict__ img, const float* __restrict__ g,
    const float* __restrict__ b, float* __restrict__ out) {
  int t = blockIdx.x;                 // token 0..12543
  int bi = t / NTOK, n = t % NTOK;
  int ph = n / 14, pw = n % 14;
  __shared__ float vals[PD];
  __shared__ float red[256];
  int tid = threadIdx.x;
  for (int j = tid; j < PD; j += 256) {
    int p1 = j / 48, rem = j % 48, p2 = rem / 3, c = rem % 3;
    vals[j] = img[(((long)bi*3 + c)*224 + (ph*16 + p1))*224 + (pw*16 + p2)];
  }
  __syncthreads();
  float s = 0.f;
  for (int j = tid; j < PD; j += 256) s += vals[j];
  red[tid] = s; __syncthreads();
  for (int st = 128; st > 0; st >>= 1) { if (tid < st) red[tid] += red[tid+st]; __syncthreads(); }
  float mean = red[0] / (float)PD;
  __syncthreads();
  float s2 = 0.f;
  for (int j = tid; j < PD; j += 256) { float d = vals[j]-mean; s2 += d*d; }
  red[tid] = s2; __syncthreads();
  for (int st = 128; st > 0; st >>= 1) { if (tid < st) red[tid] += red[tid+st]; __syncthreads(); }
  float rstd = rsqrtf(red[0]/(float)PD + LN_EPS);
  for (int j = tid; j < PD; j += 256)
    out[(long)t*PD + j] = (vals[j]-mean)*rstd*g[j] + b[j];
}

// ---------------- LayerNorm rows (dim<=1024), optional pos add ----------------
__global__ __launch_bounds__(256) void ln_rows(
    const float* __restrict__ in, const float* __restrict__ g,
    const float* __restrict__ b, const float* __restrict__ pos,
    float* __restrict__ out, int dim) {
  long t = blockIdx.x;
  __shared__ float vals[DIMD];
  __shared__ float red[256];
  int tid = threadIdx.x;
  const float* row = in + t*dim;
  for (int j = tid; j < dim; j += 256) vals[j] = row[j];
  __syncthreads();
  float s = 0.f;
  for (int j = tid; j < dim; j += 256) s += vals[j];
  red[tid] = s; __syncthreads();
  for (int st = 128; st > 0; st >>= 1) { if (tid < st) red[tid] += red[tid+st]; __syncthreads(); }
  float mean = red[0] / (float)dim;
  __syncthreads();
  float s2 = 0.f;
  for (int j = tid; j < dim; j += 256) { float d = vals[j]-mean; s2 += d*d; }
  red[tid] = s2; __syncthreads();
  for (int st = 128; st > 0; st >>= 1) { if (tid < st) red[tid] += red[tid+st]; __syncthreads(); }
  float rstd = rsqrtf(red[0]/(float)dim + LN_EPS);
  const float* prow = pos ? (pos + (long)(t % NTOK)*dim) : nullptr;
  for (int j = tid; j < dim; j += 256) {
    float v = (vals[j]-mean)*rstd*g[j] + b[j];
    if (prow) v += prow[j];
    out[t*dim + j] = v;
  }
}

// ---------------- generic tiled fp32 GEMM: C = alpha*A@B (+bias)(+add) ----------------
#define BM 64
#define BN 64
#define BK 16
__global__ __launch_bounds__(256) void gemm_nn(
    const float* __restrict__ A, const float* __restrict__ B,
    const float* __restrict__ bias, const float* __restrict__ addp,
    float* __restrict__ C,
    int M, int N, int K, int lda, int ldb, int ldc,
    long aB, long bB, long cB, float alpha) {
  int z = blockIdx.z;
  A += (long)z*aB; B += (long)z*bB; C += (long)z*cB;
  const float* addz = addp ? addp + (long)z*cB : nullptr;
  __shared__ float As[BK][BM];
  __shared__ float Bs[BK][BN];
  int bm = blockIdx.y*BM, bn = blockIdx.x*BN;
  int tid = threadIdx.x;
  int tm = (tid/16)*4, tn = (tid%16)*4;
  int am = tid/4, ak = (tid%4)*4;
  int bk = tid/64, bn0 = tid%64;
  float acc[4][4] = {};
  for (int k0 = 0; k0 < K; k0 += BK) {
    #pragma unroll
    for (int i = 0; i < 4; i++) {
      int kk = ak + i;
      As[kk][am] = (bm+am < M && k0+kk < K) ? A[(long)(bm+am)*lda + k0+kk] : 0.f;
    }
    #pragma unroll
    for (int i = 0; i < 4; i++) {
      int kk = bk + i*4;
      Bs[kk][bn0] = (k0+kk < K && bn+bn0 < N) ? B[(long)(k0+kk)*ldb + bn+bn0] : 0.f;
    }
    __syncthreads();
    #pragma unroll
    for (int kk = 0; kk < BK; kk++) {
      float a[4], bb[4];
      #pragma unroll
      for (int i = 0; i < 4; i++) a[i] = As[kk][tm+i];
      #pragma unroll
      for (int j = 0; j < 4; j++) bb[j] = Bs[kk][tn+j];
      #pragma unroll
      for (int i = 0; i < 4; i++)
        #pragma unroll
        for (int j = 0; j < 4; j++)
          acc[i][j] = fmaf(a[i], bb[j], acc[i][j]);
    }
    __syncthreads();
  }
  #pragma unroll
  for (int i = 0; i < 4; i++)
    #pragma unroll
    for (int j = 0; j < 4; j++) {
      int m = bm+tm+i, n = bn+tn+j;
      if (m < M && n < N) {
        float v = acc[i][j]*alpha;
        if (bias) v += bias[n];
        if (addz) v += addz[(long)m*ldc + n];
        C[(long)m*ldc + n] = v;
      }
    }
}

// ---------------- NT GEMM: C = alpha * A @ B^T (B row-major [N,K]) ----------------
__global__ __launch_bounds__(256) void gemm_nt(
    const float* __restrict__ A, const float* __restrict__ B,
    float* __restrict__ C,
    int M, int N, int K, int lda, int ldb, int ldc,
    long aB, long bB, long cB, float alpha) {
  int z = blockIdx.z;
  A += (long)z*aB; B += (long)z*bB; C += (long)z*cB;
  __shared__ float As[BK][BM];
  __shared__ float Bs[BK][BN];
  int bm = blockIdx.y*BM, bn = blockIdx.x*BN;
  int tid = threadIdx.x;
  int tm = (tid/16)*4, tn = (tid%16)*4;
  int am = tid/4, ak = (tid%4)*4;
  float acc[4][4] = {};
  for (int k0 = 0; k0 < K; k0 += BK) {
    #pragma unroll
    for (int i = 0; i < 4; i++) {
      int kk = ak + i;
      As[kk][am] = (bm+am < M && k0+kk < K) ? A[(long)(bm+am)*lda + k0+kk] : 0.f;
      Bs[kk][am] = (bn+am < N && k0+kk < K) ? B[(long)(bn+am)*ldb + k0+kk] : 0.f;
    }
    __syncthreads();
    #pragma unroll
    for (int kk = 0; kk < BK; kk++) {
      float a[4], bb[4];
      #pragma unroll
      for (int i = 0; i < 4; i++) a[i] = As[kk][tm+i];
      #pragma unroll
      for (int j = 0; j < 4; j++) bb[j] = Bs[kk][tn+j];
      #pragma unroll
      for (int i = 0; i < 4; i++)
        #pragma unroll
        for (int j = 0; j < 4; j++)
          acc[i][j] = fmaf(a[i], bb[j], acc[i][j]);
    }
    __syncthreads();
  }
  #pragma unroll
  for (int i = 0; i < 4; i++)
    #pragma unroll
    for (int j = 0; j < 4; j++) {
      int m = bm+tm+i, n = bn+tn+j;
      if (m < M && n < N) C[(long)m*ldc + n] = acc[i][j]*alpha;
    }
}

// ---------------- row softmax over 196 entries ----------------
__global__ __launch_bounds__(256) void softmax_rows(float* __restrict__ S) {
  long r = blockIdx.x;
  float* row = S + r*NTOK;
  __shared__ float red[256];
  int tid = threadIdx.x;
  float v = (tid < NTOK) ? row[tid] : -INFINITY;
  red[tid] = v; __syncthreads();
  for (int st = 128; st > 0; st >>= 1) { if (tid < st) red[tid] = fmaxf(red[tid], red[tid+st]); __syncthreads(); }
  float mx = red[0]; __syncthreads();
  float e = (tid < NTOK) ? __expf(v - mx) : 0.f;
  red[tid] = e; __syncthreads();
  for (int st = 128; st > 0; st >>= 1) { if (tid < st) red[tid] += red[tid+st]; __syncthreads(); }
  float inv = 1.f / red[0];
  if (tid < NTOK) row[tid] = e * inv;
}

// ---------------- mean over tokens per batch ----------------
__global__ __launch_bounds__(256) void mean_tokens(
    const float* __restrict__ x, float* __restrict__ out) {
  int b = blockIdx.x, tid = threadIdx.x;
  #pragma unroll
  for (int i = 0; i < 4; i++) {
    int d = tid + i*256;
    float s = 0.f;
    for (int n = 0; n < NTOK; n++) s += x[((long)b*NTOK + n)*DIMD + d];
    out[(long)b*DIMD + d] = s * (1.f/(float)NTOK);
  }
}

extern "C" void kernel_launch(void* const* d_in, const int* in_sizes, int n_in,
                              void* d_out, int out_size, void* d_ws, size_t ws_size,
                              hipStream_t stream) {
  (void)in_sizes; (void)n_in; (void)out_size; (void)ws_size;
  const float* image = (const float*)d_in[0];
  const float* ln1_g = (const float*)d_in[1];
  const float* ln1_b = (const float*)d_in[2];
  const float* W_emb = (const float*)d_in[3];
  const float* b_emb = (const float*)d_in[4];
  const float* ln2_g = (const float*)d_in[5];
  const float* ln2_b = (const float*)d_in[6];
  const float* pos   = (const float*)d_in[7];
  const float* norm_g= (const float*)d_in[8];
  const float* norm_b= (const float*)d_in[9];
  const float* WV    = (const float*)d_in[10];
  const float* WK    = (const float*)d_in[11];
  const float* WQ    = (const float*)d_in[12];
  const float* lastW = (const float*)d_in[13];
  const float* lastb = (const float*)d_in[14];
  float* out = (float*)d_out;

  float* ws = (float*)d_ws;
  const long S0 = (long)TOKENS*DIMD;           // 12,845,056 floats
  float* x    = ws;            // (12544,1024)
  float* xn   = ws + S0;       // (12544,1024)  (also embed temp E)
  float* q    = ws + 2*S0;     // (12544,1024)  (also Xp (12544,768), also G)
  float* k    = ws + 3*S0;     // (12544,1024)
  float* Aatt = ws + 4*S0;     // (64,196,196)
  float* meanx = Aatt + (long)BATCH*NTOK*NTOK; // (64,1024)

  dim3 blk(256);
  const float scale = 0.08838834764831845f;    // 128^-0.5

  // patch embed
  patchify_ln<<<TOKENS, blk, 0, stream>>>(image, ln1_g, ln1_b, q);
  gemm_nn<<<dim3(DIMD/BN, TOKENS/BM, 1), blk, 0, stream>>>(
      q, W_emb, b_emb, nullptr, xn, TOKENS, DIMD, PD, PD, DIMD, DIMD, 0, 0, 0, 1.f);
  ln_rows<<<TOKENS, blk, 0, stream>>>(xn, ln2_g, ln2_b, pos, x, DIMD);

  for (int l = 0; l < DEPTH; l++) {
    ln_rows<<<TOKENS, blk, 0, stream>>>(x, norm_g, norm_b, nullptr, xn, DIMD);
    gemm_nn<<<dim3(DIMD/BN, TOKENS/BM, 1), blk, 0, stream>>>(
        xn, WQ, nullptr, nullptr, q, TOKENS, DIMD, DIMD, DIMD, DIMD, DIMD, 0, 0, 0, 1.f);
    gemm_nn<<<dim3(DIMD/BN, TOKENS/BM, 1), blk, 0, stream>>>(
        xn, WK, nullptr, nullptr, k, TOKENS, DIMD, DIMD, DIMD, DIMD, DIMD, 0, 0, 0, 1.f);
    gemm_nt<<<dim3(4, 4, BATCH), blk, 0, stream>>>(
        q, k, Aatt, NTOK, NTOK, DIMD, DIMD, DIMD, NTOK,
        (long)NTOK*DIMD, (long)NTOK*DIMD, (long)NTOK*NTOK, scale);
    softmax_rows<<<BATCH*NTOK, blk, 0, stream>>>(Aatt);
    // G = per-head xn @ WV  -> q buffer (q is dead now)
    gemm_nn<<<dim3(2, TOKENS/BM, HEADS), blk, 0, stream>>>(
        xn, WV, nullptr, nullptr, q, TOKENS, HD, HD, DIMD, HD, DIMD, HD, 0, HD, 1.f);
    // x = A @ G + xn
    gemm_nn<<<dim3(DIMD/BN, 4, BATCH), blk, 0, stream>>>(
        Aatt, q, nullptr, xn, x, NTOK, DIMD, NTOK, NTOK, DIMD, DIMD,
        (long)NTOK*NTOK, (long)NTOK*DIMD, (long)NTOK*DIMD, 1.f);
  }

  mean_tokens<<<BATCH, blk, 0, stream>>>(x, meanx);
  gemm_nn<<<dim3(16, 1, 1), blk, 0, stream>>>(
      meanx, lastW, lastb, nullptr, out, BATCH, 1000, DIMD, DIMD, 1000, 1000, 0, 0, 0, 1.f);
}

// Round 2
// 2264.661 us; speedup vs baseline: 4.1341x; 4.1341x over previous
//
#include <hip/hip_runtime.h>
#include <hip/hip_bf16.h>
#include <math.h>

#define NTOK   196
#define BATCH  64
#define TOKENS (BATCH*NTOK)   // 12544
#define DIMD   1024
#define PD     768
#define HEADS  8
#define HD     128
#define DEPTH  6
#define LN_EPS 1e-5f
#define APAD_R 256            // padded A rows per batch (for 128-tiles)
#define APAD_C 224            // padded K dim for A@G (7*32)

typedef __hip_bfloat16 bf16;
typedef __attribute__((ext_vector_type(8))) short bf16x8;
typedef __attribute__((ext_vector_type(4))) float f32x4;

typedef const __attribute__((address_space(1))) void* gptr_t;
typedef __attribute__((address_space(3))) void* lptr_t;

__device__ __forceinline__ void gl_lds16(const bf16* g, bf16* l) {
  __builtin_amdgcn_global_load_lds((gptr_t)(const void*)g, (lptr_t)(void*)l, 16, 0, 0);
}
__device__ __forceinline__ unsigned short bfbits(float f) {
  bf16 h = __float2bfloat16(f);
  return *(unsigned short*)&h;
}

// ================= MFMA GEMM: C[m][n] = sum_k A[m][k] * Bt[n][k] =================
// A: bf16 [.,lda]; Bt: bf16 [N][ldb] (i.e. B transposed); 128x128 tile, BK=32.
// mode 0: Cf = acc*alpha (+bias[n]) (+res), bounds Mb/Nb
// mode 1: Cb = bf16(acc)
// mode 2: Gt special: Cb[(b*DIMD + z*HD + gn)*APAD_C + (gm - b*NTOK)] = bf16(acc)
__global__ __launch_bounds__(256) void gemm_mfma(
    const bf16* __restrict__ A, int lda, long aStride,
    const bf16* __restrict__ Bt, int ldb, long bStride,
    int K, int mode,
    float* __restrict__ Cf, bf16* __restrict__ Cb, int ldc, long cStride,
    const float* __restrict__ bias, const float* __restrict__ res, long resStride,
    float alpha, int Mb, int Nb) {
  __shared__ __align__(16) bf16 As[128*32];
  __shared__ __align__(16) bf16 Bs[128*32];
  const int z = blockIdx.z;
  A  += (long)z*aStride;
  Bt += (long)z*bStride;
  const int m0 = blockIdx.y*128, n0 = blockIdx.x*128;
  const int tid = threadIdx.x, lane = tid & 63, wv = tid >> 6;
  const int lrow = lane >> 2, lchunk = lane & 3;       // staging: 4 lanes per 32-elem row
  const bf16* ga = A + (long)(m0 + wv*32 + lrow)*lda + lchunk*8;
  const bf16* gb = Bt + (long)(n0 + wv*32 + lrow)*ldb + lchunk*8;
  bf16* lA = As + (wv*32)*32;
  bf16* lB = Bs + (wv*32)*32;
  const int mBase = (wv & 1)*64, nBase = (wv >> 1)*64;
  const int fr = lane & 15, fq = lane >> 4;

  f32x4 acc[4][4];
  #pragma unroll
  for (int i = 0; i < 4; i++)
    #pragma unroll
    for (int j = 0; j < 4; j++) acc[i][j] = (f32x4){0.f,0.f,0.f,0.f};

  for (int k0 = 0; k0 < K; k0 += 32) {
    gl_lds16(ga + k0,            lA);
    gl_lds16(ga + k0 + 16*lda,   lA + 16*32);
    gl_lds16(gb + k0,            lB);
    gl_lds16(gb + k0 + 16*ldb,   lB + 16*32);
    asm volatile("s_waitcnt vmcnt(0)" ::: "memory");
    __syncthreads();
    bf16x8 af[4], bfr[4];
    #pragma unroll
    for (int mi = 0; mi < 4; mi++)
      af[mi] = *(const bf16x8*)(As + (mBase + mi*16 + fr)*32 + fq*8);
    #pragma unroll
    for (int ni = 0; ni < 4; ni++)
      bfr[ni] = *(const bf16x8*)(Bs + (nBase + ni*16 + fr)*32 + fq*8);
    #pragma unroll
    for (int mi = 0; mi < 4; mi++)
      #pragma unroll
      for (int ni = 0; ni < 4; ni++)
        acc[mi][ni] = __builtin_amdgcn_mfma_f32_16x16x32_bf16(af[mi], bfr[ni], acc[mi][ni], 0, 0, 0);
    __syncthreads();
  }

  // epilogue
  const int hOff = z * HD;  // mode 2
  #pragma unroll
  for (int mi = 0; mi < 4; mi++)
    #pragma unroll
    for (int ni = 0; ni < 4; ni++)
      #pragma unroll
      for (int r = 0; r < 4; r++) {
        int gm = m0 + mBase + mi*16 + fq*4 + r;
        int gn = n0 + nBase + ni*16 + fr;
        if (gm >= Mb || gn >= Nb) continue;
        float v = acc[mi][ni][r] * alpha;
        if (mode == 0) {
          if (bias) v += bias[gn];
          if (res)  v += res[(long)z*resStride + (long)gm*ldc + gn];
          Cf[(long)z*cStride + (long)gm*ldc + gn] = v;
        } else if (mode == 1) {
          Cb[(long)z*cStride + (long)gm*ldc + gn] = __float2bfloat16(v);
        } else {
          int b = gm / NTOK;
          int mt = gm - b*NTOK;
          Cb[((long)b*DIMD + hOff + gn)*APAD_C + mt] = __float2bfloat16(v);
        }
      }
}

// ================= patchify + LN1 (dim 768) -> bf16 =================
__global__ __launch_bounds__(256) void patchify_ln(
    const float* __restrict__ img, const float* __restrict__ g,
    const float* __restrict__ b, bf16* __restrict__ out) {
  int t = blockIdx.x;
  int bi = t / NTOK, n = t % NTOK;
  int ph = n / 14, pw = n % 14;
  __shared__ float vals[PD];
  __shared__ float red[256];
  int tid = threadIdx.x;
  for (int j = tid; j < PD; j += 256) {
    int p1 = j / 48, rem = j % 48, p2 = rem / 3, c = rem % 3;
    vals[j] = img[(((long)bi*3 + c)*224 + (ph*16 + p1))*224 + (pw*16 + p2)];
  }
  __syncthreads();
  float s = 0.f;
  for (int j = tid; j < PD; j += 256) s += vals[j];
  red[tid] = s; __syncthreads();
  for (int st = 128; st > 0; st >>= 1) { if (tid < st) red[tid] += red[tid+st]; __syncthreads(); }
  float mean = red[0] / (float)PD;
  __syncthreads();
  float s2 = 0.f;
  for (int j = tid; j < PD; j += 256) { float d = vals[j]-mean; s2 += d*d; }
  red[tid] = s2; __syncthreads();
  for (int st = 128; st > 0; st >>= 1) { if (tid < st) red[tid] += red[tid+st]; __syncthreads(); }
  float rstd = rsqrtf(red[0]/(float)PD + LN_EPS);
  for (int j = tid; j < PD; j += 256)
    out[(long)t*PD + j] = __float2bfloat16((vals[j]-mean)*rstd*g[j] + b[j]);
}

// ================= LayerNorm rows (dim=1024) fp32 out + optional bf16 out =================
__global__ __launch_bounds__(256) void ln_rows2(
    const float* __restrict__ in, const float* __restrict__ g,
    const float* __restrict__ b, const float* __restrict__ pos,
    float* __restrict__ outf, ushort4* __restrict__ outb) {
  long t = blockIdx.x;
  int tid = threadIdx.x;
  float4 v = ((const float4*)(in + t*DIMD))[tid];
  float s  = v.x+v.y+v.z+v.w;
  float s2 = v.x*v.x+v.y*v.y+v.z*v.z+v.w*v.w;
  __shared__ float rs[256], rq[256];
  rs[tid]=s; rq[tid]=s2; __syncthreads();
  for (int st = 128; st > 0; st >>= 1) {
    if (tid < st) { rs[tid]+=rs[tid+st]; rq[tid]+=rq[tid+st]; }
    __syncthreads();
  }
  float mean = rs[0]*(1.f/1024.f);
  float var  = rq[0]*(1.f/1024.f) - mean*mean;
  float rstd = rsqrtf(var + LN_EPS);
  float4 gg = ((const float4*)g)[tid];
  float4 bb = ((const float4*)b)[tid];
  float4 o;
  o.x = (v.x-mean)*rstd*gg.x + bb.x;
  o.y = (v.y-mean)*rstd*gg.y + bb.y;
  o.z = (v.z-mean)*rstd*gg.z + bb.z;
  o.w = (v.w-mean)*rstd*gg.w + bb.w;
  if (pos) {
    float4 pp = ((const float4*)(pos + (long)(t % NTOK)*DIMD))[tid];
    o.x += pp.x; o.y += pp.y; o.z += pp.z; o.w += pp.w;
  }
  if (outf) ((float4*)(outf + t*DIMD))[tid] = o;
  if (outb) {
    ushort4 u;
    u.x = bfbits(o.x); u.y = bfbits(o.y); u.z = bfbits(o.z); u.w = bfbits(o.w);
    outb[t*256 + tid] = u;
  }
}

// ================= cast + transpose: src fp32 [R][C] -> dst bf16 [C][R] =================
__global__ void castT(const float* __restrict__ src, bf16* __restrict__ dst, int R, int C) {
  __shared__ float t[32][33];
  int rb = blockIdx.y*32, cb = blockIdx.x*32;
  int tx = threadIdx.x, ty = threadIdx.y;  // (32,8)
  for (int i = ty; i < 32; i += 8)
    if (rb+i < R && cb+tx < C) t[i][tx] = src[(long)(rb+i)*C + cb+tx];
  __syncthreads();
  for (int i = ty; i < 32; i += 8)
    if (cb+i < C && rb+tx < R) dst[(long)(cb+i)*R + rb+tx] = __float2bfloat16(t[tx][i]);
}

// ================= softmax over 196 logits -> bf16 A padded to 224 cols =================
__global__ __launch_bounds__(256) void softmax_pad(
    const float* __restrict__ logits, bf16* __restrict__ Apad) {
  int r = blockIdx.x;              // 0..BATCH*NTOK-1
  int z = r / NTOK, rq = r % NTOK;
  const float* row = logits + ((long)z*NTOK + rq)*NTOK;
  __shared__ float red[256];
  int tid = threadIdx.x;
  float v = (tid < NTOK) ? row[tid] : -INFINITY;
  red[tid] = v; __syncthreads();
  for (int st = 128; st > 0; st >>= 1) { if (tid < st) red[tid] = fmaxf(red[tid], red[tid+st]); __syncthreads(); }
  float mx = red[0]; __syncthreads();
  float e = (tid < NTOK) ? __expf(v - mx) : 0.f;
  red[tid] = e; __syncthreads();
  for (int st = 128; st > 0; st >>= 1) { if (tid < st) red[tid] += red[tid+st]; __syncthreads(); }
  float inv = 1.f / red[0];
  if (tid < APAD_C)
    Apad[((long)z*APAD_R + rq)*APAD_C + tid] = __float2bfloat16(tid < NTOK ? e*inv : 0.f);
}

// ================= mean over tokens =================
__global__ __launch_bounds__(256) void mean_tokens(
    const float* __restrict__ x, float* __restrict__ out) {
  int b = blockIdx.x, tid = threadIdx.x;
  #pragma unroll
  for (int i = 0; i < 4; i++) {
    int d = tid + i*256;
    float s = 0.f;
    for (int n = 0; n < NTOK; n++) s += x[((long)b*NTOK + n)*DIMD + d];
    out[(long)b*DIMD + d] = s * (1.f/(float)NTOK);
  }
}

// ================= small fp32 GEMM (final classifier only) =================
#define BM 64
#define BN 64
#define BK 16
__global__ __launch_bounds__(256) void gemm_nn(
    const float* __restrict__ A, const float* __restrict__ B,
    const float* __restrict__ bias, float* __restrict__ C,
    int M, int N, int K, int lda, int ldb, int ldc) {
  __shared__ float As[BK][BM];
  __shared__ float Bs[BK][BN];
  int bm = blockIdx.y*BM, bn = blockIdx.x*BN;
  int tid = threadIdx.x;
  int tm = (tid/16)*4, tn = (tid%16)*4;
  int am = tid/4, ak = (tid%4)*4;
  int bk = tid/64, bn0 = tid%64;
  float acc[4][4] = {};
  for (int k0 = 0; k0 < K; k0 += BK) {
    #pragma unroll
    for (int i = 0; i < 4; i++) {
      int kk = ak + i;
      As[kk][am] = (bm+am < M && k0+kk < K) ? A[(long)(bm+am)*lda + k0+kk] : 0.f;
    }
    #pragma unroll
    for (int i = 0; i < 4; i++) {
      int kk = bk + i*4;
      Bs[kk][bn0] = (k0+kk < K && bn+bn0 < N) ? B[(long)(k0+kk)*ldb + bn+bn0] : 0.f;
    }
    __syncthreads();
    #pragma unroll
    for (int kk = 0; kk < BK; kk++) {
      float a[4], bb[4];
      #pragma unroll
      for (int i = 0; i < 4; i++) a[i] = As[kk][tm+i];
      #pragma unroll
      for (int j = 0; j < 4; j++) bb[j] = Bs[kk][tn+j];
      #pragma unroll
      for (int i = 0; i < 4; i++)
        #pragma unroll
        for (int j = 0; j < 4; j++)
          acc[i][j] = fmaf(a[i], bb[j], acc[i][j]);
    }
    __syncthreads();
  }
  #pragma unroll
  for (int i = 0; i < 4; i++)
    #pragma unroll
    for (int j = 0; j < 4; j++) {
      int m = bm+tm+i, n = bn+tn+j;
      if (m < M && n < N) C[(long)m*ldc + n] = acc[i][j] + (bias ? bias[n] : 0.f);
    }
}

extern "C" void kernel_launch(void* const* d_in, const int* in_sizes, int n_in,
                              void* d_out, int out_size, void* d_ws, size_t ws_size,
                              hipStream_t stream) {
  (void)in_sizes; (void)n_in; (void)out_size; (void)ws_size;
  const float* image = (const float*)d_in[0];
  const float* ln1_g = (const float*)d_in[1];
  const float* ln1_b = (const float*)d_in[2];
  const float* W_emb = (const float*)d_in[3];
  const float* b_emb = (const float*)d_in[4];
  const float* ln2_g = (const float*)d_in[5];
  const float* ln2_b = (const float*)d_in[6];
  const float* pos   = (const float*)d_in[7];
  const float* norm_g= (const float*)d_in[8];
  const float* norm_b= (const float*)d_in[9];
  const float* WV    = (const float*)d_in[10];
  const float* WK    = (const float*)d_in[11];
  const float* WQ    = (const float*)d_in[12];
  const float* lastW = (const float*)d_in[13];
  const float* lastb = (const float*)d_in[14];
  float* out = (float*)d_out;

  char* W = (char*)d_ws;
  float* x    = (float*)(W);                       // 51,380,224 B
  float* xn   = (float*)(W + 51380224);            // 51,380,224
  bf16*  xnb  = (bf16*) (W + 102760448);           // 25,690,112
  bf16*  qb   = (bf16*) (W + 128450560);           // 25,821,184 (12608 rows)
  bf16*  kb   = (bf16*) (W + 154271744);           // 25,821,184
  bf16*  Gt   = qb;                                // 29,360,128 <= qb+kb (both dead)
  char*  slab = W + 180092928;                     // 19,267,584
  bf16*  Xp   = (bf16*) slab;                      // 19,267,584 (embed phase only)
  float* logits = (float*)slab;                    //  9,834,496 (layer phase)
  bf16*  Apad = (bf16*) (slab + 9834496);          //  7,340,032
  char*  wts  = W + 199360512;
  bf16*  WembT= (bf16*)(wts);                      // 1,572,864
  bf16*  WQt  = (bf16*)(wts + 1572864);            // 2,097,152
  bf16*  WKt  = (bf16*)(wts + 3670016);            // 2,097,152
  bf16*  WVt  = (bf16*)(wts + 5767168);            //    32,768
  float* meanx= (float*)(wts + 5799936);           //   262,144

  dim3 blk(256);
  const float scale = 0.08838834764831845f;  // 128^-0.5
  const long ZR = 0;

  // weight casts (transposed to [N][K])
  castT<<<dim3(32, 24), dim3(32, 8), 0, stream>>>(W_emb, WembT, PD, DIMD);
  castT<<<dim3(32, 32), dim3(32, 8), 0, stream>>>(WQ, WQt, DIMD, DIMD);
  castT<<<dim3(32, 32), dim3(32, 8), 0, stream>>>(WK, WKt, DIMD, DIMD);
  castT<<<dim3(4, 4),  dim3(32, 8), 0, stream>>>(WV, WVt, HD, HD);

  // patch embed
  patchify_ln<<<TOKENS, blk, 0, stream>>>(image, ln1_g, ln1_b, Xp);
  gemm_mfma<<<dim3(8, 98, 1), blk, 0, stream>>>(
      Xp, PD, ZR, WembT, PD, ZR, PD, 0,
      xn, nullptr, DIMD, ZR, b_emb, nullptr, ZR, 1.f, TOKENS, DIMD);
  ln_rows2<<<TOKENS, blk, 0, stream>>>(xn, ln2_g, ln2_b, pos, x, nullptr);

  for (int l = 0; l < DEPTH; l++) {
    ln_rows2<<<TOKENS, blk, 0, stream>>>(x, norm_g, norm_b, nullptr, xn, (ushort4*)xnb);
    gemm_mfma<<<dim3(8, 98, 1), blk, 0, stream>>>(
        xnb, DIMD, ZR, WQt, DIMD, ZR, DIMD, 1,
        nullptr, qb, DIMD, ZR, nullptr, nullptr, ZR, 1.f, TOKENS, DIMD);
    gemm_mfma<<<dim3(8, 98, 1), blk, 0, stream>>>(
        xnb, DIMD, ZR, WKt, DIMD, ZR, DIMD, 1,
        nullptr, kb, DIMD, ZR, nullptr, nullptr, ZR, 1.f, TOKENS, DIMD);
    // logits = q @ k^T * scale  (k natural layout == B^T layout)
    gemm_mfma<<<dim3(2, 2, BATCH), blk, 0, stream>>>(
        qb, DIMD, (long)NTOK*DIMD, kb, DIMD, (long)NTOK*DIMD, DIMD, 0,
        logits, nullptr, NTOK, (long)NTOK*NTOK, nullptr, nullptr, ZR, scale, NTOK, NTOK);
    softmax_pad<<<BATCH*NTOK, blk, 0, stream>>>(logits, Apad);
    // Gt[b][dim][token] = (xn_head @ WV)^T   (overwrites q/k)
    gemm_mfma<<<dim3(1, 98, HEADS), blk, 0, stream>>>(
        xnb, DIMD, (long)HD, WVt, HD, ZR, HD, 2,
        nullptr, Gt, 0, ZR, nullptr, nullptr, ZR, 1.f, TOKENS, HD);
    // x = A @ G + xn
    gemm_mfma<<<dim3(8, 2, BATCH), blk, 0, stream>>>(
        Apad, APAD_C, (long)APAD_R*APAD_C, Gt, APAD_C, (long)DIMD*APAD_C, APAD_C, 0,
        x, nullptr, DIMD, (long)NTOK*DIMD, nullptr, xn, (long)NTOK*DIMD, 1.f, NTOK, DIMD);
  }

  mean_tokens<<<BATCH, blk, 0, stream>>>(x, meanx);
  gemm_nn<<<dim3(16, 1, 1), blk, 0, stream>>>(
      meanx, lastW, lastb, out, BATCH, 1000, DIMD, DIMD, 1000, 1000);
}

// Round 3
// 1870.790 us; speedup vs baseline: 5.0045x; 1.2105x over previous
//
#include <hip/hip_runtime.h>
#include <hip/hip_bf16.h>
#include <math.h>

#define NTOK   196
#define BATCH  64
#define TOKENS (BATCH*NTOK)   // 12544
#define DIMD   1024
#define PD     768
#define HEADS  8
#define HD     128
#define DEPTH  6
#define LN_EPS 1e-5f
#define APAD_R 256            // padded A rows per batch (for 128-tiles)
#define APAD_C 224            // padded K dim for A@G (7*32)

typedef __hip_bfloat16 bf16;
typedef __attribute__((ext_vector_type(8))) short bf16x8;
typedef __attribute__((ext_vector_type(4))) float f32x4;

typedef const __attribute__((address_space(1))) void* gptr_t;
typedef __attribute__((address_space(3))) void* lptr_t;

__device__ __forceinline__ void gl_lds16(const bf16* g, bf16* l) {
  __builtin_amdgcn_global_load_lds((gptr_t)(const void*)g, (lptr_t)(void*)l, 16, 0, 0);
}
__device__ __forceinline__ unsigned short bfbits(float f) {
  bf16 h = __float2bfloat16(f);
  return *(unsigned short*)&h;
}

// ================= MFMA GEMM: C[m][n] = sum_k A[m][k] * Bt[n][k] =================
// A: bf16 [.,lda]; Bt: bf16 [N][ldb]; 128x128 tile, BK=32.
// mode 0: Cf = acc*alpha (+bias[n]) (+res), bounds Mb/Nb
// mode 1: Cb = bf16(acc)
// mode 2: Gt special: Cb[(b*DIMD + z*HD + gn)*APAD_C + (gm - b*NTOK)] = bf16(acc)
__global__ __launch_bounds__(256) void gemm_mfma(
    const bf16* __restrict__ A, int lda, long aStride,
    const bf16* __restrict__ Bt, int ldb, long bStride,
    int K, int mode,
    float* __restrict__ Cf, bf16* __restrict__ Cb, int ldc, long cStride,
    const float* __restrict__ bias, const float* __restrict__ res, long resStride,
    float alpha, int Mb, int Nb) {
  __shared__ __align__(16) bf16 As[128*32];
  __shared__ __align__(16) bf16 Bs[128*32];
  const int z = blockIdx.z;
  A  += (long)z*aStride;
  Bt += (long)z*bStride;
  const int m0 = blockIdx.y*128, n0 = blockIdx.x*128;
  const int tid = threadIdx.x, lane = tid & 63, wv = tid >> 6;
  const int lrow = lane >> 2, lchunk = lane & 3;
  const bf16* ga = A + (long)(m0 + wv*32 + lrow)*lda + lchunk*8;
  const bf16* gb = Bt + (long)(n0 + wv*32 + lrow)*ldb + lchunk*8;
  bf16* lA = As + (wv*32)*32;
  bf16* lB = Bs + (wv*32)*32;
  const int mBase = (wv & 1)*64, nBase = (wv >> 1)*64;
  const int fr = lane & 15, fq = lane >> 4;

  f32x4 acc[4][4];
  #pragma unroll
  for (int i = 0; i < 4; i++)
    #pragma unroll
    for (int j = 0; j < 4; j++) acc[i][j] = (f32x4){0.f,0.f,0.f,0.f};

  for (int k0 = 0; k0 < K; k0 += 32) {
    gl_lds16(ga + k0,            lA);
    gl_lds16(ga + k0 + 16*lda,   lA + 16*32);
    gl_lds16(gb + k0,            lB);
    gl_lds16(gb + k0 + 16*ldb,   lB + 16*32);
    asm volatile("s_waitcnt vmcnt(0)" ::: "memory");
    __syncthreads();
    bf16x8 af[4], bfr[4];
    #pragma unroll
    for (int mi = 0; mi < 4; mi++)
      af[mi] = *(const bf16x8*)(As + (mBase + mi*16 + fr)*32 + fq*8);
    #pragma unroll
    for (int ni = 0; ni < 4; ni++)
      bfr[ni] = *(const bf16x8*)(Bs + (nBase + ni*16 + fr)*32 + fq*8);
    #pragma unroll
    for (int mi = 0; mi < 4; mi++)
      #pragma unroll
      for (int ni = 0; ni < 4; ni++)
        acc[mi][ni] = __builtin_amdgcn_mfma_f32_16x16x32_bf16(af[mi], bfr[ni], acc[mi][ni], 0, 0, 0);
    __syncthreads();
  }

  const int hOff = z * HD;  // mode 2
  #pragma unroll
  for (int mi = 0; mi < 4; mi++)
    #pragma unroll
    for (int ni = 0; ni < 4; ni++)
      #pragma unroll
      for (int r = 0; r < 4; r++) {
        int gm = m0 + mBase + mi*16 + fq*4 + r;
        int gn = n0 + nBase + ni*16 + fr;
        if (gm >= Mb || gn >= Nb) continue;
        float v = acc[mi][ni][r] * alpha;
        if (mode == 0) {
          if (bias) v += bias[gn];
          if (res)  v += res[(long)z*resStride + (long)gm*ldc + gn];
          Cf[(long)z*cStride + (long)gm*ldc + gn] = v;
        } else if (mode == 1) {
          Cb[(long)z*cStride + (long)gm*ldc + gn] = __float2bfloat16(v);
        } else {
          int b = gm / NTOK;
          int mt = gm - b*NTOK;
          Cb[((long)b*DIMD + hOff + gn)*APAD_C + mt] = __float2bfloat16(v);
        }
      }
}

// ================= classifier: split-K MFMA, M=64, N tiles of 128, K chunks of 128 =================
// A [64][1024] bf16, Bt [1024][1024] bf16 (rows>=1000 garbage, masked in reduce)
// Cp [8][64][1024] fp32 partials
__global__ __launch_bounds__(256) void gemm_cls(
    const bf16* __restrict__ A, const bf16* __restrict__ Bt,
    float* __restrict__ Cp) {
  __shared__ __align__(16) bf16 As[64*32];
  __shared__ __align__(16) bf16 Bs[128*32];
  const int n0 = blockIdx.x*128, kz = blockIdx.y;
  const int tid = threadIdx.x, lane = tid & 63, wv = tid >> 6;
  const bf16* ga = A + (tid>>2)*DIMD + kz*128 + (tid&3)*8;
  const bf16* gb = Bt + (long)(n0 + wv*32 + (lane>>2))*DIMD + kz*128 + (lane&3)*8;
  bf16* lA = As + wv*512;
  bf16* lB = Bs + (wv*32)*32;
  const int fr = lane & 15, fq = lane >> 4;
  f32x4 acc[4][2];
  #pragma unroll
  for (int i = 0; i < 4; i++)
    #pragma unroll
    for (int j = 0; j < 2; j++) acc[i][j] = (f32x4){0.f,0.f,0.f,0.f};
  for (int it = 0; it < 4; it++) {
    gl_lds16(ga + it*32, lA);
    gl_lds16(gb + it*32,            lB);
    gl_lds16(gb + it*32 + 16*DIMD,  lB + 16*32);
    asm volatile("s_waitcnt vmcnt(0)" ::: "memory");
    __syncthreads();
    bf16x8 af[4], bfr[2];
    #pragma unroll
    for (int mi = 0; mi < 4; mi++)
      af[mi] = *(const bf16x8*)(As + (mi*16 + fr)*32 + fq*8);
    #pragma unroll
    for (int ni = 0; ni < 2; ni++)
      bfr[ni] = *(const bf16x8*)(Bs + (wv*32 + ni*16 + fr)*32 + fq*8);
    #pragma unroll
    for (int mi = 0; mi < 4; mi++)
      #pragma unroll
      for (int ni = 0; ni < 2; ni++)
        acc[mi][ni] = __builtin_amdgcn_mfma_f32_16x16x32_bf16(af[mi], bfr[ni], acc[mi][ni], 0, 0, 0);
    __syncthreads();
  }
  #pragma unroll
  for (int mi = 0; mi < 4; mi++)
    #pragma unroll
    for (int ni = 0; ni < 2; ni++)
      #pragma unroll
      for (int r = 0; r < 4; r++) {
        int gm = mi*16 + fq*4 + r;
        int gn = n0 + wv*32 + ni*16 + fr;
        Cp[((long)kz*64 + gm)*DIMD + gn] = acc[mi][ni][r];
      }
}

__global__ __launch_bounds__(256) void cls_reduce(
    const float* __restrict__ Cp, const float* __restrict__ bias,
    float* __restrict__ out) {
  int i = blockIdx.x*256 + threadIdx.x;   // 0..63999
  int m = i / 1000, n = i - m*1000;
  float s = bias[n];
  #pragma unroll
  for (int kz = 0; kz < 8; kz++) s += Cp[((long)kz*64 + m)*DIMD + n];
  out[i] = s;
}

// ================= patchify + LN1 (dim 768) -> bf16 =================
__global__ __launch_bounds__(256) void patchify_ln(
    const float* __restrict__ img, const float* __restrict__ g,
    const float* __restrict__ b, bf16* __restrict__ out) {
  int t = blockIdx.x;
  int bi = t / NTOK, n = t % NTOK;
  int ph = n / 14, pw = n % 14;
  __shared__ float vals[PD];
  __shared__ float red[256];
  int tid = threadIdx.x;
  for (int j = tid; j < PD; j += 256) {
    int p1 = j / 48, rem = j % 48, p2 = rem / 3, c = rem % 3;
    vals[j] = img[(((long)bi*3 + c)*224 + (ph*16 + p1))*224 + (pw*16 + p2)];
  }
  __syncthreads();
  float s = 0.f;
  for (int j = tid; j < PD; j += 256) s += vals[j];
  red[tid] = s; __syncthreads();
  for (int st = 128; st > 0; st >>= 1) { if (tid < st) red[tid] += red[tid+st]; __syncthreads(); }
  float mean = red[0] / (float)PD;
  __syncthreads();
  float s2 = 0.f;
  for (int j = tid; j < PD; j += 256) { float d = vals[j]-mean; s2 += d*d; }
  red[tid] = s2; __syncthreads();
  for (int st = 128; st > 0; st >>= 1) { if (tid < st) red[tid] += red[tid+st]; __syncthreads(); }
  float rstd = rsqrtf(red[0]/(float)PD + LN_EPS);
  for (int j = tid; j < PD; j += 256)
    out[(long)t*PD + j] = __float2bfloat16((vals[j]-mean)*rstd*g[j] + b[j]);
}

// ================= LayerNorm rows (dim=1024) fp32 out + optional bf16 out =================
__global__ __launch_bounds__(256) void ln_rows2(
    const float* __restrict__ in, const float* __restrict__ g,
    const float* __restrict__ b, const float* __restrict__ pos,
    float* __restrict__ outf, ushort4* __restrict__ outb) {
  long t = blockIdx.x;
  int tid = threadIdx.x;
  float4 v = ((const float4*)(in + t*DIMD))[tid];
  float s  = v.x+v.y+v.z+v.w;
  float s2 = v.x*v.x+v.y*v.y+v.z*v.z+v.w*v.w;
  __shared__ float rs[256], rq[256];
  rs[tid]=s; rq[tid]=s2; __syncthreads();
  for (int st = 128; st > 0; st >>= 1) {
    if (tid < st) { rs[tid]+=rs[tid+st]; rq[tid]+=rq[tid+st]; }
    __syncthreads();
  }
  float mean = rs[0]*(1.f/1024.f);
  float var  = rq[0]*(1.f/1024.f) - mean*mean;
  float rstd = rsqrtf(var + LN_EPS);
  float4 gg = ((const float4*)g)[tid];
  float4 bb = ((const float4*)b)[tid];
  float4 o;
  o.x = (v.x-mean)*rstd*gg.x + bb.x;
  o.y = (v.y-mean)*rstd*gg.y + bb.y;
  o.z = (v.z-mean)*rstd*gg.z + bb.z;
  o.w = (v.w-mean)*rstd*gg.w + bb.w;
  if (pos) {
    float4 pp = ((const float4*)(pos + (long)(t % NTOK)*DIMD))[tid];
    o.x += pp.x; o.y += pp.y; o.z += pp.z; o.w += pp.w;
  }
  if (outf) ((float4*)(outf + t*DIMD))[tid] = o;
  if (outb) {
    ushort4 u;
    u.x = bfbits(o.x); u.y = bfbits(o.y); u.z = bfbits(o.z); u.w = bfbits(o.w);
    outb[t*256 + tid] = u;
  }
}

// ================= cast + transpose: src fp32 [R][C] -> dst bf16 [C][R] =================
__global__ void castT(const float* __restrict__ src, bf16* __restrict__ dst, int R, int C) {
  __shared__ float t[32][33];
  int rb = blockIdx.y*32, cb = blockIdx.x*32;
  int tx = threadIdx.x, ty = threadIdx.y;  // (32,8)
  for (int i = ty; i < 32; i += 8)
    if (rb+i < R && cb+tx < C) t[i][tx] = src[(long)(rb+i)*C + cb+tx];
  __syncthreads();
  for (int i = ty; i < 32; i += 8)
    if (cb+i < C && rb+tx < R) dst[(long)(cb+i)*R + rb+tx] = __float2bfloat16(t[tx][i]);
}

// ================= softmax over 196 logits -> bf16 A padded to 224 cols =================
__global__ __launch_bounds__(256) void softmax_pad(
    const float* __restrict__ logits, bf16* __restrict__ Apad) {
  int r = blockIdx.x;
  int z = r / NTOK, rq = r % NTOK;
  const float* row = logits + ((long)z*NTOK + rq)*NTOK;
  __shared__ float red[256];
  int tid = threadIdx.x;
  float v = (tid < NTOK) ? row[tid] : -INFINITY;
  red[tid] = v; __syncthreads();
  for (int st = 128; st > 0; st >>= 1) { if (tid < st) red[tid] = fmaxf(red[tid], red[tid+st]); __syncthreads(); }
  float mx = red[0]; __syncthreads();
  float e = (tid < NTOK) ? __expf(v - mx) : 0.f;
  red[tid] = e; __syncthreads();
  for (int st = 128; st > 0; st >>= 1) { if (tid < st) red[tid] += red[tid+st]; __syncthreads(); }
  float inv = 1.f / red[0];
  if (tid < APAD_C)
    Apad[((long)z*APAD_R + rq)*APAD_C + tid] = __float2bfloat16(tid < NTOK ? e*inv : 0.f);
}

// ================= mean over tokens -> bf16 =================
__global__ __launch_bounds__(256) void mean_tokens(
    const float* __restrict__ x, bf16* __restrict__ outb) {
  int b = blockIdx.x;
  int d = blockIdx.y*256 + threadIdx.x;
  const float* p = x + (long)b*NTOK*DIMD + d;
  float s = 0.f;
  #pragma unroll 4
  for (int n = 0; n < NTOK; n++) s += p[(long)n*DIMD];
  outb[(long)b*DIMD + d] = __float2bfloat16(s * (1.f/196.f));
}

extern "C" void kernel_launch(void* const* d_in, const int* in_sizes, int n_in,
                              void* d_out, int out_size, void* d_ws, size_t ws_size,
                              hipStream_t stream) {
  (void)in_sizes; (void)n_in; (void)out_size; (void)ws_size;
  const float* image = (const float*)d_in[0];
  const float* ln1_g = (const float*)d_in[1];
  const float* ln1_b = (const float*)d_in[2];
  const float* W_emb = (const float*)d_in[3];
  const float* b_emb = (const float*)d_in[4];
  const float* ln2_g = (const float*)d_in[5];
  const float* ln2_b = (const float*)d_in[6];
  const float* pos   = (const float*)d_in[7];
  const float* norm_g= (const float*)d_in[8];
  const float* norm_b= (const float*)d_in[9];
  const float* WV    = (const float*)d_in[10];
  const float* WK    = (const float*)d_in[11];
  const float* WQ    = (const float*)d_in[12];
  const float* lastW = (const float*)d_in[13];
  const float* lastb = (const float*)d_in[14];
  float* out = (float*)d_out;

  char* W = (char*)d_ws;
  float* x     = (float*)(W);                      // 51,380,224
  float* xn    = (float*)(W + 51380224);           // 51,380,224 (lastWT aliases at end)
  bf16*  xnb   = (bf16*) (W + 102760448);          // 25,690,112
  bf16*  qkb   = (bf16*) (W + 128450560);          // 12608x2048 bf16 = 51,642,368
  bf16*  Xp    = qkb;                              // embed-phase alias
  bf16*  Gt    = qkb;                              // post-softmax alias (29.4 MB)
  char*  slab  = W + 180092928;                    // 17,174,528
  float* logits= (float*)slab;                     //  9,834,496
  bf16*  Apad  = (bf16*)(slab + 9834496);          //  7,340,032
  bf16*  meanxb= (bf16*)slab;                      //    131,072 (end phase)
  float* clsPart=(float*)(slab + 131072);          //  2,097,152 (end phase)
  bf16*  WembT = (bf16*)(W + 197267456);           //  1,572,864
  bf16*  WQKt  = (bf16*)(W + 198840320);           //  4,194,304
  bf16*  WVt   = (bf16*)(W + 203034624);           //     32,768
  bf16*  lastWT= (bf16*)xn;                        //  2,097,152 (cast after last layer)

  dim3 blk(256);
  const float scale = 0.08838834764831845f;  // 128^-0.5
  const long ZR = 0;

  // weight casts (transposed to [N][K])
  castT<<<dim3(32, 24), dim3(32, 8), 0, stream>>>(W_emb, WembT, PD, DIMD);
  castT<<<dim3(32, 32), dim3(32, 8), 0, stream>>>(WQ, WQKt, DIMD, DIMD);
  castT<<<dim3(32, 32), dim3(32, 8), 0, stream>>>(WK, WQKt + (long)DIMD*DIMD, DIMD, DIMD);
  castT<<<dim3(4, 4),  dim3(32, 8), 0, stream>>>(WV, WVt, HD, HD);

  // patch embed
  patchify_ln<<<TOKENS, blk, 0, stream>>>(image, ln1_g, ln1_b, Xp);
  gemm_mfma<<<dim3(8, 98, 1), blk, 0, stream>>>(
      Xp, PD, ZR, WembT, PD, ZR, PD, 0,
      xn, nullptr, DIMD, ZR, b_emb, nullptr, ZR, 1.f, TOKENS, DIMD);
  ln_rows2<<<TOKENS, blk, 0, stream>>>(xn, ln2_g, ln2_b, pos, x, nullptr);

  for (int l = 0; l < DEPTH; l++) {
    ln_rows2<<<TOKENS, blk, 0, stream>>>(x, norm_g, norm_b, nullptr, xn, (ushort4*)xnb);
    // fused Q|K: qkb[m][0:1024]=q, [1024:2048]=k
    gemm_mfma<<<dim3(16, 98, 1), blk, 0, stream>>>(
        xnb, DIMD, ZR, WQKt, DIMD, ZR, DIMD, 1,
        nullptr, qkb, 2048, ZR, nullptr, nullptr, ZR, 1.f, TOKENS, 2048);
    // logits = q @ k^T * scale
    gemm_mfma<<<dim3(2, 2, BATCH), blk, 0, stream>>>(
        qkb, 2048, (long)NTOK*2048, qkb + DIMD, 2048, (long)NTOK*2048, DIMD, 0,
        logits, nullptr, NTOK, (long)NTOK*NTOK, nullptr, nullptr, ZR, scale, NTOK, NTOK);
    softmax_pad<<<BATCH*NTOK, blk, 0, stream>>>(logits, Apad);
    // Gt[b][dim][token] = (xn_head @ WV)^T   (overwrites qkb)
    gemm_mfma<<<dim3(1, 98, HEADS), blk, 0, stream>>>(
        xnb, DIMD, (long)HD, WVt, HD, ZR, HD, 2,
        nullptr, Gt, 0, ZR, nullptr, nullptr, ZR, 1.f, TOKENS, HD);
    // x = A @ G + xn
    gemm_mfma<<<dim3(8, 2, BATCH), blk, 0, stream>>>(
        Apad, APAD_C, (long)APAD_R*APAD_C, Gt, APAD_C, (long)DIMD*APAD_C, APAD_C, 0,
        x, nullptr, DIMD, (long)NTOK*DIMD, nullptr, xn, (long)NTOK*DIMD, 1.f, NTOK, DIMD);
  }

  // classifier: mean -> bf16, lastW -> bf16^T (into dead xn), split-K MFMA, reduce
  mean_tokens<<<dim3(BATCH, 4), blk, 0, stream>>>(x, meanxb);
  castT<<<dim3(32, 32), dim3(32, 8), 0, stream>>>(lastW, lastWT, DIMD, 1000);
  gemm_cls<<<dim3(8, 8), blk, 0, stream>>>(meanxb, lastWT, clsPart);
  cls_reduce<<<250, blk, 0, stream>>>(clsPart, lastb, out);
}

// Round 5
// 1691.759 us; speedup vs baseline: 5.5341x; 1.1058x over previous
//
#include <hip/hip_runtime.h>
#include <hip/hip_bf16.h>
#include <math.h>

#define NTOK   196
#define BATCH  64
#define TOKENS (BATCH*NTOK)   // 12544
#define DIMD   1024
#define PD     768
#define HEADS  8
#define HD     128
#define DEPTH  6
#define LN_EPS 1e-5f
#define APAD_R 256            // padded A rows per batch (for 128-tiles)
#define APAD_C 224            // padded K dim for A@G (7*32)

typedef __hip_bfloat16 bf16;
typedef __attribute__((ext_vector_type(8))) short bf16x8;
typedef __attribute__((ext_vector_type(4))) float f32x4;

typedef const __attribute__((address_space(1))) void* gptr_t;
typedef __attribute__((address_space(3))) void* lptr_t;

__device__ __forceinline__ void gl_lds16(const bf16* g, bf16* l) {
  __builtin_amdgcn_global_load_lds((gptr_t)(const void*)g, (lptr_t)(void*)l, 16, 0, 0);
}
__device__ __forceinline__ unsigned short bfbits(float f) {
  bf16 h = __float2bfloat16(f);
  return *(unsigned short*)&h;
}

// ================= generic MFMA GEMM: C[m][n] = sum_k A[m][k] * Bt[n][k] =================
// 128x128 tile, BK=32. mode 0: Cf = acc*alpha (+bias)(+bf16 res); mode 1: Cb = bf16(acc)
__global__ __launch_bounds__(256) void gemm_mfma(
    const bf16* __restrict__ A, int lda, long aStride,
    const bf16* __restrict__ Bt, int ldb, long bStride,
    int K, int mode,
    float* __restrict__ Cf, bf16* __restrict__ Cb, int ldc, long cStride,
    const float* __restrict__ bias, const bf16* __restrict__ resb, long resStride,
    float alpha, int Mb, int Nb) {
  __shared__ __align__(16) bf16 As[128*32];
  __shared__ __align__(16) bf16 Bs[128*32];
  const int z = blockIdx.z;
  A  += (long)z*aStride;
  Bt += (long)z*bStride;
  const int m0 = blockIdx.y*128, n0 = blockIdx.x*128;
  const int tid = threadIdx.x, lane = tid & 63, wv = tid >> 6;
  const int lrow = lane >> 2, lchunk = lane & 3;
  const bf16* ga = A + (long)(m0 + wv*32 + lrow)*lda + lchunk*8;
  const bf16* gb = Bt + (long)(n0 + wv*32 + lrow)*ldb + lchunk*8;
  bf16* lA = As + (wv*32)*32;
  bf16* lB = Bs + (wv*32)*32;
  const int mBase = (wv & 1)*64, nBase = (wv >> 1)*64;
  const int fr = lane & 15, fq = lane >> 4;

  f32x4 acc[4][4];
  #pragma unroll
  for (int i = 0; i < 4; i++)
    #pragma unroll
    for (int j = 0; j < 4; j++) acc[i][j] = (f32x4){0.f,0.f,0.f,0.f};

  for (int k0 = 0; k0 < K; k0 += 32) {
    gl_lds16(ga + k0,            lA);
    gl_lds16(ga + k0 + 16*lda,   lA + 16*32);
    gl_lds16(gb + k0,            lB);
    gl_lds16(gb + k0 + 16*ldb,   lB + 16*32);
    asm volatile("s_waitcnt vmcnt(0)" ::: "memory");
    __syncthreads();
    bf16x8 af[4], bfr[4];
    #pragma unroll
    for (int mi = 0; mi < 4; mi++)
      af[mi] = *(const bf16x8*)(As + (mBase + mi*16 + fr)*32 + fq*8);
    #pragma unroll
    for (int ni = 0; ni < 4; ni++)
      bfr[ni] = *(const bf16x8*)(Bs + (nBase + ni*16 + fr)*32 + fq*8);
    #pragma unroll
    for (int mi = 0; mi < 4; mi++)
      #pragma unroll
      for (int ni = 0; ni < 4; ni++)
        acc[mi][ni] = __builtin_amdgcn_mfma_f32_16x16x32_bf16(af[mi], bfr[ni], acc[mi][ni], 0, 0, 0);
    __syncthreads();
  }

  #pragma unroll
  for (int mi = 0; mi < 4; mi++)
    #pragma unroll
    for (int ni = 0; ni < 4; ni++)
      #pragma unroll
      for (int r = 0; r < 4; r++) {
        int gm = m0 + mBase + mi*16 + fq*4 + r;
        int gn = n0 + nBase + ni*16 + fr;
        if (gm >= Mb || gn >= Nb) continue;
        float v = acc[mi][ni][r] * alpha;
        if (mode == 0) {
          if (bias) v += bias[gn];
          if (resb) v += __bfloat162float(resb[(long)z*resStride + (long)gm*ldc + gn]);
          Cf[(long)z*cStride + (long)gm*ldc + gn] = v;
        } else {
          Cb[(long)z*cStride + (long)gm*ldc + gn] = __float2bfloat16(v);
        }
      }
}

// ================= QKT: per-batch 196x196x1024, 64x64 tiles =================
__global__ __launch_bounds__(256) void gemm_qkt(
    const bf16* __restrict__ qk, float* __restrict__ logits, float scale) {
  __shared__ __align__(16) bf16 As[64*32];
  __shared__ __align__(16) bf16 Bs[64*32];
  const int z = blockIdx.z;
  const bf16* A  = qk + (long)z*NTOK*2048;        // q rows, lda 2048
  const bf16* Bt = A + DIMD;                      // k rows
  const int m0 = blockIdx.y*64, n0 = blockIdx.x*64;
  const int tid = threadIdx.x, lane = tid & 63, wv = tid >> 6;
  const int lrow = lane >> 2, lchunk = lane & 3;
  const bf16* ga = A  + (long)(m0 + wv*16 + lrow)*2048 + lchunk*8;
  const bf16* gb = Bt + (long)(n0 + wv*16 + lrow)*2048 + lchunk*8;
  bf16* lA = As + (wv*16)*32;
  bf16* lB = Bs + (wv*16)*32;
  const int mBase = (wv & 1)*32, nBase = (wv >> 1)*32;
  const int fr = lane & 15, fq = lane >> 4;

  f32x4 acc[2][2];
  #pragma unroll
  for (int i = 0; i < 2; i++)
    #pragma unroll
    for (int j = 0; j < 2; j++) acc[i][j] = (f32x4){0.f,0.f,0.f,0.f};

  for (int k0 = 0; k0 < 1024; k0 += 32) {
    gl_lds16(ga + k0, lA);
    gl_lds16(gb + k0, lB);
    asm volatile("s_waitcnt vmcnt(0)" ::: "memory");
    __syncthreads();
    bf16x8 af[2], bfr[2];
    #pragma unroll
    for (int mi = 0; mi < 2; mi++)
      af[mi] = *(const bf16x8*)(As + (mBase + mi*16 + fr)*32 + fq*8);
    #pragma unroll
    for (int ni = 0; ni < 2; ni++)
      bfr[ni] = *(const bf16x8*)(Bs + (nBase + ni*16 + fr)*32 + fq*8);
    #pragma unroll
    for (int mi = 0; mi < 2; mi++)
      #pragma unroll
      for (int ni = 0; ni < 2; ni++)
        acc[mi][ni] = __builtin_amdgcn_mfma_f32_16x16x32_bf16(af[mi], bfr[ni], acc[mi][ni], 0, 0, 0);
    __syncthreads();
  }

  #pragma unroll
  for (int mi = 0; mi < 2; mi++)
    #pragma unroll
    for (int ni = 0; ni < 2; ni++)
      #pragma unroll
      for (int r = 0; r < 4; r++) {
        int gm = m0 + mBase + mi*16 + fq*4 + r;
        int gn = n0 + nBase + ni*16 + fr;
        if (gm < NTOK && gn < NTOK)
          logits[(long)z*NTOK*NTOK + (long)gm*NTOK + gn] = acc[mi][ni][r] * scale;
      }
}

// ================= transpose Gnat [b*196+t][1024] -> Gt [b][1024][224] (pad cols zeroed) =====
__global__ void transposeG(const bf16* __restrict__ Gnat, bf16* __restrict__ Gt) {
  __shared__ unsigned short sm[64][66];
  const int b = blockIdx.z;
  const int d0 = blockIdx.x*64, t0 = blockIdx.y*64;
  const int tx = threadIdx.x, ty = threadIdx.y;   // (32,8)
  const unsigned short* src = (const unsigned short*)Gnat;
  unsigned short* dst = (unsigned short*)Gt;
  for (int i = ty; i < 64; i += 8) {
    int t = t0 + i;
    if (t < NTOK) {
      ushort2 v = *(const ushort2*)(src + ((long)(b*NTOK + t))*DIMD + d0 + 2*tx);
      sm[2*tx][i] = v.x;
      sm[2*tx+1][i] = v.y;
    }
  }
  __syncthreads();
  for (int i = ty; i < 64; i += 8) {
    int d = d0 + i;
    int t = t0 + 2*tx;
    if (t < APAD_C) {
      ushort2 v;
      if (t < NTOK) { v.x = sm[i][2*tx]; v.y = sm[i][2*tx+1]; }
      else          { v.x = 0; v.y = 0; }            // zero pad cols 196..223
      *(ushort2*)(dst + ((long)b*DIMD + d)*APAD_C + t) = v;
    }
  }
}

// ================= classifier split-K =================
__global__ __launch_bounds__(256) void gemm_cls(
    const bf16* __restrict__ A, const bf16* __restrict__ Bt,
    float* __restrict__ Cp) {
  __shared__ __align__(16) bf16 As[64*32];
  __shared__ __align__(16) bf16 Bs[128*32];
  const int n0 = blockIdx.x*128, kz = blockIdx.y;
  const int tid = threadIdx.x, lane = tid & 63, wv = tid >> 6;
  const bf16* ga = A + (tid>>2)*DIMD + kz*128 + (tid&3)*8;
  const bf16* gb = Bt + (long)(n0 + wv*32 + (lane>>2))*DIMD + kz*128 + (lane&3)*8;
  bf16* lA = As + wv*512;
  bf16* lB = Bs + (wv*32)*32;
  const int fr = lane & 15, fq = lane >> 4;
  f32x4 acc[4][2];
  #pragma unroll
  for (int i = 0; i < 4; i++)
    #pragma unroll
    for (int j = 0; j < 2; j++) acc[i][j] = (f32x4){0.f,0.f,0.f,0.f};
  for (int it = 0; it < 4; it++) {
    gl_lds16(ga + it*32, lA);
    gl_lds16(gb + it*32,            lB);
    gl_lds16(gb + it*32 + 16*DIMD,  lB + 16*32);
    asm volatile("s_waitcnt vmcnt(0)" ::: "memory");
    __syncthreads();
    bf16x8 af[4], bfr[2];
    #pragma unroll
    for (int mi = 0; mi < 4; mi++)
      af[mi] = *(const bf16x8*)(As + (mi*16 + fr)*32 + fq*8);
    #pragma unroll
    for (int ni = 0; ni < 2; ni++)
      bfr[ni] = *(const bf16x8*)(Bs + (wv*32 + ni*16 + fr)*32 + fq*8);
    #pragma unroll
    for (int mi = 0; mi < 4; mi++)
      #pragma unroll
      for (int ni = 0; ni < 2; ni++)
        acc[mi][ni] = __builtin_amdgcn_mfma_f32_16x16x32_bf16(af[mi], bfr[ni], acc[mi][ni], 0, 0, 0);
    __syncthreads();
  }
  #pragma unroll
  for (int mi = 0; mi < 4; mi++)
    #pragma unroll
    for (int ni = 0; ni < 2; ni++)
      #pragma unroll
      for (int r = 0; r < 4; r++) {
        int gm = mi*16 + fq*4 + r;
        int gn = n0 + wv*32 + ni*16 + fr;
        Cp[((long)kz*64 + gm)*DIMD + gn] = acc[mi][ni][r];
      }
}

__global__ __launch_bounds__(256) void cls_reduce(
    const float* __restrict__ Cp, const float* __restrict__ bias,
    float* __restrict__ out) {
  int i = blockIdx.x*256 + threadIdx.x;
  int m = i / 1000, n = i - m*1000;
  float s = bias[n];
  #pragma unroll
  for (int kz = 0; kz < 8; kz++) s += Cp[((long)kz*64 + m)*DIMD + n];
  out[i] = s;
}

// ================= patchify + LN1 (dim 768) -> bf16 =================
__global__ __launch_bounds__(256) void patchify_ln(
    const float* __restrict__ img, const float* __restrict__ g,
    const float* __restrict__ b, bf16* __restrict__ out) {
  int t = blockIdx.x;
  int bi = t / NTOK, n = t % NTOK;
  int ph = n / 14, pw = n % 14;
  __shared__ float vals[PD];
  __shared__ float red[256];
  int tid = threadIdx.x;
  for (int j = tid; j < PD; j += 256) {
    int p1 = j / 48, rem = j % 48, p2 = rem / 3, c = rem % 3;
    vals[j] = img[(((long)bi*3 + c)*224 + (ph*16 + p1))*224 + (pw*16 + p2)];
  }
  __syncthreads();
  float s = 0.f;
  for (int j = tid; j < PD; j += 256) s += vals[j];
  red[tid] = s; __syncthreads();
  for (int st = 128; st > 0; st >>= 1) { if (tid < st) red[tid] += red[tid+st]; __syncthreads(); }
  float mean = red[0] / (float)PD;
  __syncthreads();
  float s2 = 0.f;
  for (int j = tid; j < PD; j += 256) { float d = vals[j]-mean; s2 += d*d; }
  red[tid] = s2; __syncthreads();
  for (int st = 128; st > 0; st >>= 1) { if (tid < st) red[tid] += red[tid+st]; __syncthreads(); }
  float rstd = rsqrtf(red[0]/(float)PD + LN_EPS);
  for (int j = tid; j < PD; j += 256)
    out[(long)t*PD + j] = __float2bfloat16((vals[j]-mean)*rstd*g[j] + b[j]);
}

// ================= LayerNorm rows (dim=1024): optional fp32 out, optional bf16 out =================
__global__ __launch_bounds__(256) void ln_rows2(
    const float* __restrict__ in, const float* __restrict__ g,
    const float* __restrict__ b, const float* __restrict__ pos,
    float* __restrict__ outf, ushort4* __restrict__ outb) {
  long t = blockIdx.x;
  int tid = threadIdx.x;
  float4 v = ((const float4*)(in + t*DIMD))[tid];
  float s  = v.x+v.y+v.z+v.w;
  float s2 = v.x*v.x+v.y*v.y+v.z*v.z+v.w*v.w;
  __shared__ float rs[256], rq[256];
  rs[tid]=s; rq[tid]=s2; __syncthreads();
  for (int st = 128; st > 0; st >>= 1) {
    if (tid < st) { rs[tid]+=rs[tid+st]; rq[tid]+=rq[tid+st]; }
    __syncthreads();
  }
  float mean = rs[0]*(1.f/1024.f);
  float var  = rq[0]*(1.f/1024.f) - mean*mean;
  float rstd = rsqrtf(var + LN_EPS);
  float4 gg = ((const float4*)g)[tid];
  float4 bb = ((const float4*)b)[tid];
  float4 o;
  o.x = (v.x-mean)*rstd*gg.x + bb.x;
  o.y = (v.y-mean)*rstd*gg.y + bb.y;
  o.z = (v.z-mean)*rstd*gg.z + bb.z;
  o.w = (v.w-mean)*rstd*gg.w + bb.w;
  if (pos) {
    float4 pp = ((const float4*)(pos + (long)(t % NTOK)*DIMD))[tid];
    o.x += pp.x; o.y += pp.y; o.z += pp.z; o.w += pp.w;
  }
  if (outf) ((float4*)(outf + t*DIMD))[tid] = o;
  if (outb) {
    ushort4 u;
    u.x = bfbits(o.x); u.y = bfbits(o.y); u.z = bfbits(o.z); u.w = bfbits(o.w);
    outb[t*256 + tid] = u;
  }
}

// ================= cast + transpose weights: fp32 [R][C] -> bf16 [C][R] =================
__global__ void castT(const float* __restrict__ src, bf16* __restrict__ dst, int R, int C) {
  __shared__ float t[32][33];
  int rb = blockIdx.y*32, cb = blockIdx.x*32;
  int tx = threadIdx.x, ty = threadIdx.y;  // (32,8)
  for (int i = ty; i < 32; i += 8)
    if (rb+i < R && cb+tx < C) t[i][tx] = src[(long)(rb+i)*C + cb+tx];
  __syncthreads();
  for (int i = ty; i < 32; i += 8)
    if (cb+i < C && rb+tx < R) dst[(long)(cb+i)*R + rb+tx] = __float2bfloat16(t[tx][i]);
}

// ================= softmax over 196 logits -> bf16 A padded to 256x224 (pads zeroed) =====
__global__ __launch_bounds__(256) void softmax_pad(
    const float* __restrict__ logits, bf16* __restrict__ Apad) {
  int r = blockIdx.x;              // 0..BATCH*256-1
  int z = r >> 8, rq = r & 255;
  int tid = threadIdx.x;
  if (rq >= NTOK) {                // zero pad rows 196..255
    if (tid < APAD_C)
      Apad[((long)z*APAD_R + rq)*APAD_C + tid] = __float2bfloat16(0.f);
    return;
  }
  const float* row = logits + ((long)z*NTOK + rq)*NTOK;
  __shared__ float red[256];
  float v = (tid < NTOK) ? row[tid] : -INFINITY;
  red[tid] = v; __syncthreads();
  for (int st = 128; st > 0; st >>= 1) { if (tid < st) red[tid] = fmaxf(red[tid], red[tid+st]); __syncthreads(); }
  float mx = red[0]; __syncthreads();
  float e = (tid < NTOK) ? __expf(v - mx) : 0.f;
  red[tid] = e; __syncthreads();
  for (int st = 128; st > 0; st >>= 1) { if (tid < st) red[tid] += red[tid+st]; __syncthreads(); }
  float inv = 1.f / red[0];
  if (tid < APAD_C)
    Apad[((long)z*APAD_R + rq)*APAD_C + tid] = __float2bfloat16(tid < NTOK ? e*inv : 0.f);
}

// ================= mean over tokens -> bf16 =================
__global__ __launch_bounds__(256) void mean_tokens(
    const float* __restrict__ x, bf16* __restrict__ outb) {
  int b = blockIdx.x;
  int d = blockIdx.y*256 + threadIdx.x;
  const float* p = x + (long)b*NTOK*DIMD + d;
  float s = 0.f;
  #pragma unroll 4
  for (int n = 0; n < NTOK; n++) s += p[(long)n*DIMD];
  outb[(long)b*DIMD + d] = __float2bfloat16(s * (1.f/196.f));
}

extern "C" void kernel_launch(void* const* d_in, const int* in_sizes, int n_in,
                              void* d_out, int out_size, void* d_ws, size_t ws_size,
                              hipStream_t stream) {
  (void)in_sizes; (void)n_in; (void)out_size; (void)ws_size;
  const float* image = (const float*)d_in[0];
  const float* ln1_g = (const float*)d_in[1];
  const float* ln1_b = (const float*)d_in[2];
  const float* W_emb = (const float*)d_in[3];
  const float* b_emb = (const float*)d_in[4];
  const float* ln2_g = (const float*)d_in[5];
  const float* ln2_b = (const float*)d_in[6];
  const float* pos   = (const float*)d_in[7];
  const float* norm_g= (const float*)d_in[8];
  const float* norm_b= (const float*)d_in[9];
  const float* WV    = (const float*)d_in[10];
  const float* WK    = (const float*)d_in[11];
  const float* WQ    = (const float*)d_in[12];
  const float* lastW = (const float*)d_in[13];
  const float* lastb = (const float*)d_in[14];
  float* out = (float*)d_out;

  char* W = (char*)d_ws;
  float* x     = (float*)(W);                      // 51,380,224
  bf16*  xnb   = (bf16*) (W + 51380224);           // 25,690,112
  bf16*  qkb   = (bf16*) (W + 77070336);           // 12608x2048 = 51,642,368 (alias: Xp, Gnat)
  bf16*  Xp    = qkb;
  bf16*  Gnat  = qkb;
  // slabB: embed-phase xn (fp32 51.4 MB) OR layer-phase Gt+logits+Apad (46.5 MB)
  float* xn    = (float*)(W + 128712704);
  bf16*  Gt    = (bf16*) (W + 128712704);          // 29,360,128
  float* logits= (float*)(W + 158072832);          //  9,834,496
  bf16*  Apad  = (bf16*) (W + 167907328);          //  7,340,032
  bf16*  WembT = (bf16*) (W + 180092928);          //  1,572,864
  bf16*  WQKt  = (bf16*) (W + 181665792);          //  4,194,304
  bf16*  WVt   = (bf16*) (W + 185860096);          //     32,768
  bf16*  lastWT= (bf16*) (W + 185892864);          //  2,097,152
  bf16*  meanxb= (bf16*) (W + 187990016);          //    131,072
  float* clsPart=(float*)(W + 188121088);          //  2,097,152

  dim3 blk(256);
  const float scale = 0.08838834764831845f;  // 128^-0.5
  const long ZR = 0;

  // weight casts (transposed to [N][K])
  castT<<<dim3(32, 24), dim3(32, 8), 0, stream>>>(W_emb, WembT, PD, DIMD);
  castT<<<dim3(32, 32), dim3(32, 8), 0, stream>>>(WQ, WQKt, DIMD, DIMD);
  castT<<<dim3(32, 32), dim3(32, 8), 0, stream>>>(WK, WQKt + (long)DIMD*DIMD, DIMD, DIMD);
  castT<<<dim3(4, 4),  dim3(32, 8), 0, stream>>>(WV, WVt, HD, HD);
  castT<<<dim3(32, 32), dim3(32, 8), 0, stream>>>(lastW, lastWT, DIMD, 1000);

  // patch embed
  patchify_ln<<<TOKENS, blk, 0, stream>>>(image, ln1_g, ln1_b, Xp);
  gemm_mfma<<<dim3(8, 98, 1), blk, 0, stream>>>(
      Xp, PD, ZR, WembT, PD, ZR, PD, 0,
      xn, nullptr, DIMD, ZR, b_emb, nullptr, ZR, 1.f, TOKENS, DIMD);
  ln_rows2<<<TOKENS, blk, 0, stream>>>(xn, ln2_g, ln2_b, pos, x, nullptr);

  for (int l = 0; l < DEPTH; l++) {
    // xnb = bf16(LN(x))
    ln_rows2<<<TOKENS, blk, 0, stream>>>(x, norm_g, norm_b, nullptr, nullptr, (ushort4*)xnb);
    // fused Q|K via proven generic kernel
    gemm_mfma<<<dim3(16, 98, 1), blk, 0, stream>>>(
        xnb, DIMD, ZR, WQKt, DIMD, ZR, DIMD, 1,
        nullptr, qkb, 2048, ZR, nullptr, nullptr, ZR, 1.f, TOKENS, 2048);
    // logits = q @ k^T * scale
    gemm_qkt<<<dim3(4, 4, BATCH), blk, 0, stream>>>(qkb, logits, scale);
    softmax_pad<<<BATCH*APAD_R, blk, 0, stream>>>(logits, Apad);
    // Gnat[t][h*128+e] = sum_d xnb[t][h*128+d] * WV[d][e]   (overwrites qkb)
    gemm_mfma<<<dim3(1, 98, HEADS), blk, 0, stream>>>(
        xnb, DIMD, (long)HD, WVt, HD, ZR, HD, 1,
        nullptr, Gnat, DIMD, (long)HD, nullptr, nullptr, ZR, 1.f, TOKENS, HD);
    transposeG<<<dim3(16, 4, BATCH), dim3(32, 8), 0, stream>>>(Gnat, Gt);
    // x = A @ G + xnb (bf16 residual)
    gemm_mfma<<<dim3(8, 2, BATCH), blk, 0, stream>>>(
        Apad, APAD_C, (long)APAD_R*APAD_C, Gt, APAD_C, (long)DIMD*APAD_C, APAD_C, 0,
        x, nullptr, DIMD, (long)NTOK*DIMD, nullptr, xnb, (long)NTOK*DIMD, 1.f, NTOK, DIMD);
  }

  // classifier
  mean_tokens<<<dim3(BATCH, 4), blk, 0, stream>>>(x, meanxb);
  gemm_cls<<<dim3(8, 8), blk, 0, stream>>>(meanxb, lastWT, clsPart);
  cls_reduce<<<250, blk, 0, stream>>>(clsPart, lastb, out);
}

// Round 6
// 1533.316 us; speedup vs baseline: 6.1059x; 1.1033x over previous
//
#include <hip/hip_runtime.h>
#include <hip/hip_bf16.h>
#include <math.h>

#define NTOK   196
#define BATCH  64
#define TOKENS (BATCH*NTOK)   // 12544
#define DIMD   1024
#define PD     768
#define HEADS  8
#define HD     128
#define DEPTH  6
#define LN_EPS 1e-5f
#define APAD_R 256            // padded A rows per batch (for 128-tiles)
#define APAD_C 224            // padded K dim for A@G (7*32)

typedef __hip_bfloat16 bf16;
typedef __attribute__((ext_vector_type(8))) short bf16x8;
typedef __attribute__((ext_vector_type(4))) float f32x4;

typedef const __attribute__((address_space(1))) void* gptr_t;
typedef __attribute__((address_space(3))) void* lptr_t;

__device__ __forceinline__ void gl_lds16(const bf16* g, bf16* l) {
  __builtin_amdgcn_global_load_lds((gptr_t)(const void*)g, (lptr_t)(void*)l, 16, 0, 0);
}
__device__ __forceinline__ unsigned short bfbits(float f) {
  bf16 h = __float2bfloat16(f);
  return *(unsigned short*)&h;
}

// ================= generic MFMA GEMM: C[m][n] = sum_k A[m][k] * Bt[n][k] =================
// 128x128 tile, BK=32. mode 0: Cf = acc*alpha (+bias)(+bf16 res); mode 1: Cb = bf16(acc)
__global__ __launch_bounds__(256) void gemm_mfma(
    const bf16* __restrict__ A, int lda, long aStride,
    const bf16* __restrict__ Bt, int ldb, long bStride,
    int K, int mode,
    float* __restrict__ Cf, bf16* __restrict__ Cb, int ldc, long cStride,
    const float* __restrict__ bias, const bf16* __restrict__ resb, long resStride,
    float alpha, int Mb, int Nb) {
  __shared__ __align__(16) bf16 As[128*32];
  __shared__ __align__(16) bf16 Bs[128*32];
  const int z = blockIdx.z;
  A  += (long)z*aStride;
  Bt += (long)z*bStride;
  const int m0 = blockIdx.y*128, n0 = blockIdx.x*128;
  const int tid = threadIdx.x, lane = tid & 63, wv = tid >> 6;
  const int lrow = lane >> 2, lchunk = lane & 3;
  const bf16* ga = A + (long)(m0 + wv*32 + lrow)*lda + lchunk*8;
  const bf16* gb = Bt + (long)(n0 + wv*32 + lrow)*ldb + lchunk*8;
  bf16* lA = As + (wv*32)*32;
  bf16* lB = Bs + (wv*32)*32;
  const int mBase = (wv & 1)*64, nBase = (wv >> 1)*64;
  const int fr = lane & 15, fq = lane >> 4;

  f32x4 acc[4][4];
  #pragma unroll
  for (int i = 0; i < 4; i++)
    #pragma unroll
    for (int j = 0; j < 4; j++) acc[i][j] = (f32x4){0.f,0.f,0.f,0.f};

  for (int k0 = 0; k0 < K; k0 += 32) {
    gl_lds16(ga + k0,            lA);
    gl_lds16(ga + k0 + 16*lda,   lA + 16*32);
    gl_lds16(gb + k0,            lB);
    gl_lds16(gb + k0 + 16*ldb,   lB + 16*32);
    asm volatile("s_waitcnt vmcnt(0)" ::: "memory");
    __syncthreads();
    bf16x8 af[4], bfr[4];
    #pragma unroll
    for (int mi = 0; mi < 4; mi++)
      af[mi] = *(const bf16x8*)(As + (mBase + mi*16 + fr)*32 + fq*8);
    #pragma unroll
    for (int ni = 0; ni < 4; ni++)
      bfr[ni] = *(const bf16x8*)(Bs + (nBase + ni*16 + fr)*32 + fq*8);
    #pragma unroll
    for (int mi = 0; mi < 4; mi++)
      #pragma unroll
      for (int ni = 0; ni < 4; ni++)
        acc[mi][ni] = __builtin_amdgcn_mfma_f32_16x16x32_bf16(af[mi], bfr[ni], acc[mi][ni], 0, 0, 0);
    __syncthreads();
  }

  #pragma unroll
  for (int mi = 0; mi < 4; mi++)
    #pragma unroll
    for (int ni = 0; ni < 4; ni++)
      #pragma unroll
      for (int r = 0; r < 4; r++) {
        int gm = m0 + mBase + mi*16 + fq*4 + r;
        int gn = n0 + nBase + ni*16 + fr;
        if (gm >= Mb || gn >= Nb) continue;
        float v = acc[mi][ni][r] * alpha;
        if (mode == 0) {
          if (bias) v += bias[gn];
          if (resb) v += __bfloat162float(resb[(long)z*resStride + (long)gm*ldc + gn]);
          Cf[(long)z*cStride + (long)gm*ldc + gn] = v;
        } else {
          Cb[(long)z*cStride + (long)gm*ldc + gn] = __float2bfloat16(v);
        }
      }
}

// ================= QKT': logits[z] = xm[z] @ xnb[z]^T * scale, 64x64 tiles, lda/ldb 1024 =====
__global__ __launch_bounds__(256) void gemm_qkt(
    const bf16* __restrict__ Aq, const bf16* __restrict__ Bk,
    float* __restrict__ logits, float scale) {
  __shared__ __align__(16) bf16 As[64*32];
  __shared__ __align__(16) bf16 Bs[64*32];
  const int z = blockIdx.z;
  const bf16* A  = Aq + (long)z*NTOK*DIMD;
  const bf16* Bt = Bk + (long)z*NTOK*DIMD;
  const int m0 = blockIdx.y*64, n0 = blockIdx.x*64;
  const int tid = threadIdx.x, lane = tid & 63, wv = tid >> 6;
  const int lrow = lane >> 2, lchunk = lane & 3;
  const bf16* ga = A  + (long)(m0 + wv*16 + lrow)*DIMD + lchunk*8;
  const bf16* gb = Bt + (long)(n0 + wv*16 + lrow)*DIMD + lchunk*8;
  bf16* lA = As + (wv*16)*32;
  bf16* lB = Bs + (wv*16)*32;
  const int mBase = (wv & 1)*32, nBase = (wv >> 1)*32;
  const int fr = lane & 15, fq = lane >> 4;

  f32x4 acc[2][2];
  #pragma unroll
  for (int i = 0; i < 2; i++)
    #pragma unroll
    for (int j = 0; j < 2; j++) acc[i][j] = (f32x4){0.f,0.f,0.f,0.f};

  for (int k0 = 0; k0 < 1024; k0 += 32) {
    gl_lds16(ga + k0, lA);
    gl_lds16(gb + k0, lB);
    asm volatile("s_waitcnt vmcnt(0)" ::: "memory");
    __syncthreads();
    bf16x8 af[2], bfr[2];
    #pragma unroll
    for (int mi = 0; mi < 2; mi++)
      af[mi] = *(const bf16x8*)(As + (mBase + mi*16 + fr)*32 + fq*8);
    #pragma unroll
    for (int ni = 0; ni < 2; ni++)
      bfr[ni] = *(const bf16x8*)(Bs + (nBase + ni*16 + fr)*32 + fq*8);
    #pragma unroll
    for (int mi = 0; mi < 2; mi++)
      #pragma unroll
      for (int ni = 0; ni < 2; ni++)
        acc[mi][ni] = __builtin_amdgcn_mfma_f32_16x16x32_bf16(af[mi], bfr[ni], acc[mi][ni], 0, 0, 0);
    __syncthreads();
  }

  #pragma unroll
  for (int mi = 0; mi < 2; mi++)
    #pragma unroll
    for (int ni = 0; ni < 2; ni++)
      #pragma unroll
      for (int r = 0; r < 4; r++) {
        int gm = m0 + mBase + mi*16 + fq*4 + r;
        int gn = n0 + nBase + ni*16 + fr;
        if (gm < NTOK && gn < NTOK)
          logits[(long)z*NTOK*NTOK + (long)gm*NTOK + gn] = acc[mi][ni][r] * scale;
      }
}

// ================= transpose Gnat [b*196+t][1024] -> Gt [b][1024][224] (pad cols zeroed) =====
__global__ void transposeG(const bf16* __restrict__ Gnat, bf16* __restrict__ Gt) {
  __shared__ unsigned short sm[64][66];
  const int b = blockIdx.z;
  const int d0 = blockIdx.x*64, t0 = blockIdx.y*64;
  const int tx = threadIdx.x, ty = threadIdx.y;   // (32,8)
  const unsigned short* src = (const unsigned short*)Gnat;
  unsigned short* dst = (unsigned short*)Gt;
  for (int i = ty; i < 64; i += 8) {
    int t = t0 + i;
    if (t < NTOK) {
      ushort2 v = *(const ushort2*)(src + ((long)(b*NTOK + t))*DIMD + d0 + 2*tx);
      sm[2*tx][i] = v.x;
      sm[2*tx+1][i] = v.y;
    }
  }
  __syncthreads();
  for (int i = ty; i < 64; i += 8) {
    int d = d0 + i;
    int t = t0 + 2*tx;
    if (t < APAD_C) {
      ushort2 v;
      if (t < NTOK) { v.x = sm[i][2*tx]; v.y = sm[i][2*tx+1]; }
      else          { v.x = 0; v.y = 0; }            // zero pad cols 196..223
      *(ushort2*)(dst + ((long)b*DIMD + d)*APAD_C + t) = v;
    }
  }
}

// ================= classifier split-K =================
__global__ __launch_bounds__(256) void gemm_cls(
    const bf16* __restrict__ A, const bf16* __restrict__ Bt,
    float* __restrict__ Cp) {
  __shared__ __align__(16) bf16 As[64*32];
  __shared__ __align__(16) bf16 Bs[128*32];
  const int n0 = blockIdx.x*128, kz = blockIdx.y;
  const int tid = threadIdx.x, lane = tid & 63, wv = tid >> 6;
  const bf16* ga = A + (tid>>2)*DIMD + kz*128 + (tid&3)*8;
  const bf16* gb = Bt + (long)(n0 + wv*32 + (lane>>2))*DIMD + kz*128 + (lane&3)*8;
  bf16* lA = As + wv*512;
  bf16* lB = Bs + (wv*32)*32;
  const int fr = lane & 15, fq = lane >> 4;
  f32x4 acc[4][2];
  #pragma unroll
  for (int i = 0; i < 4; i++)
    #pragma unroll
    for (int j = 0; j < 2; j++) acc[i][j] = (f32x4){0.f,0.f,0.f,0.f};
  for (int it = 0; it < 4; it++) {
    gl_lds16(ga + it*32, lA);
    gl_lds16(gb + it*32,            lB);
    gl_lds16(gb + it*32 + 16*DIMD,  lB + 16*32);
    asm volatile("s_waitcnt vmcnt(0)" ::: "memory");
    __syncthreads();
    bf16x8 af[4], bfr[2];
    #pragma unroll
    for (int mi = 0; mi < 4; mi++)
      af[mi] = *(const bf16x8*)(As + (mi*16 + fr)*32 + fq*8);
    #pragma unroll
    for (int ni = 0; ni < 2; ni++)
      bfr[ni] = *(const bf16x8*)(Bs + (wv*32 + ni*16 + fr)*32 + fq*8);
    #pragma unroll
    for (int mi = 0; mi < 4; mi++)
      #pragma unroll
      for (int ni = 0; ni < 2; ni++)
        acc[mi][ni] = __builtin_amdgcn_mfma_f32_16x16x32_bf16(af[mi], bfr[ni], acc[mi][ni], 0, 0, 0);
    __syncthreads();
  }
  #pragma unroll
  for (int mi = 0; mi < 4; mi++)
    #pragma unroll
    for (int ni = 0; ni < 2; ni++)
      #pragma unroll
      for (int r = 0; r < 4; r++) {
        int gm = mi*16 + fq*4 + r;
        int gn = n0 + wv*32 + ni*16 + fr;
        Cp[((long)kz*64 + gm)*DIMD + gn] = acc[mi][ni][r];
      }
}

__global__ __launch_bounds__(256) void cls_reduce(
    const float* __restrict__ Cp, const float* __restrict__ bias,
    float* __restrict__ out) {
  int i = blockIdx.x*256 + threadIdx.x;
  int m = i / 1000, n = i - m*1000;
  float s = bias[n];
  #pragma unroll
  for (int kz = 0; kz < 8; kz++) s += Cp[((long)kz*64 + m)*DIMD + n];
  out[i] = s;
}

// ================= patchify + LN1 (dim 768) -> bf16 =================
__global__ __launch_bounds__(256) void patchify_ln(
    const float* __restrict__ img, const float* __restrict__ g,
    const float* __restrict__ b, bf16* __restrict__ out) {
  int t = blockIdx.x;
  int bi = t / NTOK, n = t % NTOK;
  int ph = n / 14, pw = n % 14;
  __shared__ float vals[PD];
  __shared__ float red[256];
  int tid = threadIdx.x;
  for (int j = tid; j < PD; j += 256) {
    int p1 = j / 48, rem = j % 48, p2 = rem / 3, c = rem % 3;
    vals[j] = img[(((long)bi*3 + c)*224 + (ph*16 + p1))*224 + (pw*16 + p2)];
  }
  __syncthreads();
  float s = 0.f;
  for (int j = tid; j < PD; j += 256) s += vals[j];
  red[tid] = s; __syncthreads();
  for (int st = 128; st > 0; st >>= 1) { if (tid < st) red[tid] += red[tid+st]; __syncthreads(); }
  float mean = red[0] / (float)PD;
  __syncthreads();
  float s2 = 0.f;
  for (int j = tid; j < PD; j += 256) { float d = vals[j]-mean; s2 += d*d; }
  red[tid] = s2; __syncthreads();
  for (int st = 128; st > 0; st >>= 1) { if (tid < st) red[tid] += red[tid+st]; __syncthreads(); }
  float rstd = rsqrtf(red[0]/(float)PD + LN_EPS);
  for (int j = tid; j < PD; j += 256)
    out[(long)t*PD + j] = __float2bfloat16((vals[j]-mean)*rstd*g[j] + b[j]);
}

// ================= LayerNorm rows (dim=1024): optional fp32 out, optional bf16 out =================
__global__ __launch_bounds__(256) void ln_rows2(
    const float* __restrict__ in, const float* __restrict__ g,
    const float* __restrict__ b, const float* __restrict__ pos,
    float* __restrict__ outf, ushort4* __restrict__ outb) {
  long t = blockIdx.x;
  int tid = threadIdx.x;
  float4 v = ((const float4*)(in + t*DIMD))[tid];
  float s  = v.x+v.y+v.z+v.w;
  float s2 = v.x*v.x+v.y*v.y+v.z*v.z+v.w*v.w;
  __shared__ float rs[256], rq[256];
  rs[tid]=s; rq[tid]=s2; __syncthreads();
  for (int st = 128; st > 0; st >>= 1) {
    if (tid < st) { rs[tid]+=rs[tid+st]; rq[tid]+=rq[tid+st]; }
    __syncthreads();
  }
  float mean = rs[0]*(1.f/1024.f);
  float var  = rq[0]*(1.f/1024.f) - mean*mean;
  float rstd = rsqrtf(var + LN_EPS);
  float4 gg = ((const float4*)g)[tid];
  float4 bb = ((const float4*)b)[tid];
  float4 o;
  o.x = (v.x-mean)*rstd*gg.x + bb.x;
  o.y = (v.y-mean)*rstd*gg.y + bb.y;
  o.z = (v.z-mean)*rstd*gg.z + bb.z;
  o.w = (v.w-mean)*rstd*gg.w + bb.w;
  if (pos) {
    float4 pp = ((const float4*)(pos + (long)(t % NTOK)*DIMD))[tid];
    o.x += pp.x; o.y += pp.y; o.z += pp.z; o.w += pp.w;
  }
  if (outf) ((float4*)(outf + t*DIMD))[tid] = o;
  if (outb) {
    ushort4 u;
    u.x = bfbits(o.x); u.y = bfbits(o.y); u.z = bfbits(o.z); u.w = bfbits(o.w);
    outb[t*256 + tid] = u;
  }
}

// ================= cast + transpose weights: fp32 [R][C] -> bf16 [C][R] =================
__global__ void castT(const float* __restrict__ src, bf16* __restrict__ dst, int R, int C) {
  __shared__ float t[32][33];
  int rb = blockIdx.y*32, cb = blockIdx.x*32;
  int tx = threadIdx.x, ty = threadIdx.y;  // (32,8)
  for (int i = ty; i < 32; i += 8)
    if (rb+i < R && cb+tx < C) t[i][tx] = src[(long)(rb+i)*C + cb+tx];
  __syncthreads();
  for (int i = ty; i < 32; i += 8)
    if (cb+i < C && rb+tx < R) dst[(long)(cb+i)*R + rb+tx] = __float2bfloat16(t[tx][i]);
}

// ================= natural cast fp32 -> bf16 (elementwise, float4) =================
__global__ __launch_bounds__(256) void castN(
    const float* __restrict__ src, ushort4* __restrict__ dst) {
  int i = blockIdx.x*256 + threadIdx.x;
  float4 v = ((const float4*)src)[i];
  ushort4 u;
  u.x = bfbits(v.x); u.y = bfbits(v.y); u.z = bfbits(v.z); u.w = bfbits(v.w);
  dst[i] = u;
}

// ================= softmax over 196 logits -> bf16 A padded to 256x224 (pads zeroed) =====
__global__ __launch_bounds__(256) void softmax_pad(
    const float* __restrict__ logits, bf16* __restrict__ Apad) {
  int r = blockIdx.x;              // 0..BATCH*256-1
  int z = r >> 8, rq = r & 255;
  int tid = threadIdx.x;
  if (rq >= NTOK) {                // zero pad rows 196..255
    if (tid < APAD_C)
      Apad[((long)z*APAD_R + rq)*APAD_C + tid] = __float2bfloat16(0.f);
    return;
  }
  const float* row = logits + ((long)z*NTOK + rq)*NTOK;
  __shared__ float red[256];
  float v = (tid < NTOK) ? row[tid] : -INFINITY;
  red[tid] = v; __syncthreads();
  for (int st = 128; st > 0; st >>= 1) { if (tid < st) red[tid] = fmaxf(red[tid], red[tid+st]); __syncthreads(); }
  float mx = red[0]; __syncthreads();
  float e = (tid < NTOK) ? __expf(v - mx) : 0.f;
  red[tid] = e; __syncthreads();
  for (int st = 128; st > 0; st >>= 1) { if (tid < st) red[tid] += red[tid+st]; __syncthreads(); }
  float inv = 1.f / red[0];
  if (tid < APAD_C)
    Apad[((long)z*APAD_R + rq)*APAD_C + tid] = __float2bfloat16(tid < NTOK ? e*inv : 0.f);
}

// ================= mean over tokens -> bf16 =================
__global__ __launch_bounds__(256) void mean_tokens(
    const float* __restrict__ x, bf16* __restrict__ outb) {
  int b = blockIdx.x;
  int d = blockIdx.y*256 + threadIdx.x;
  const float* p = x + (long)b*NTOK*DIMD + d;
  float s = 0.f;
  #pragma unroll 4
  for (int n = 0; n < NTOK; n++) s += p[(long)n*DIMD];
  outb[(long)b*DIMD + d] = __float2bfloat16(s * (1.f/196.f));
}

extern "C" void kernel_launch(void* const* d_in, const int* in_sizes, int n_in,
                              void* d_out, int out_size, void* d_ws, size_t ws_size,
                              hipStream_t stream) {
  (void)in_sizes; (void)n_in; (void)out_size; (void)ws_size;
  const float* image = (const float*)d_in[0];
  const float* ln1_g = (const float*)d_in[1];
  const float* ln1_b = (const float*)d_in[2];
  const float* W_emb = (const float*)d_in[3];
  const float* b_emb = (const float*)d_in[4];
  const float* ln2_g = (const float*)d_in[5];
  const float* ln2_b = (const float*)d_in[6];
  const float* pos   = (const float*)d_in[7];
  const float* norm_g= (const float*)d_in[8];
  const float* norm_b= (const float*)d_in[9];
  const float* WV    = (const float*)d_in[10];
  const float* WK    = (const float*)d_in[11];
  const float* WQ    = (const float*)d_in[12];
  const float* lastW = (const float*)d_in[13];
  const float* lastb = (const float*)d_in[14];
  float* out = (float*)d_out;

  char* W = (char*)d_ws;
  float* x     = (float*)(W);                      // 51,380,224
  bf16*  xnb   = (bf16*) (W + 51380224);           // 25,690,112
  bf16*  xm    = (bf16*) (W + 77070336);           // 25.7MB in 51.6MB slab (alias: Xp, Gnat)
  bf16*  Xp    = xm;
  bf16*  Gnat  = xm;
  // slabB: embed-phase xn (fp32 51.4 MB) OR layer-phase Gt+logits+Apad (46.5 MB)
  float* xn    = (float*)(W + 128712704);
  bf16*  Gt    = (bf16*) (W + 128712704);          // 29,360,128
  float* logits= (float*)(W + 158072832);          //  9,834,496
  bf16*  Apad  = (bf16*) (W + 167907328);          //  7,340,032
  bf16*  WembT = (bf16*) (W + 180092928);          //  1,572,864
  bf16*  WQb   = (bf16*) (W + 181665792);          //  2,097,152 (natural layout)
  bf16*  WKb   = (bf16*) (W + 183762944);          //  2,097,152 (natural layout)
  bf16*  WVt   = (bf16*) (W + 185860096);          //     32,768
  bf16*  lastWT= (bf16*) (W + 185892864);          //  2,097,152
  bf16*  meanxb= (bf16*) (W + 187990016);          //    131,072
  float* clsPart=(float*)(W + 188121088);          //  2,097,152
  bf16*  Mt    = (bf16*) (W + 190218240);          //  2,097,152 (M^T = WK @ WQ^T)

  dim3 blk(256);
  const float scale = 0.08838834764831845f;  // 128^-0.5
  const long ZR = 0;

  // weight casts
  castT<<<dim3(32, 24), dim3(32, 8), 0, stream>>>(W_emb, WembT, PD, DIMD);
  castN<<<1024, blk, 0, stream>>>(WQ, (ushort4*)WQb);
  castN<<<1024, blk, 0, stream>>>(WK, (ushort4*)WKb);
  castT<<<dim3(4, 4),  dim3(32, 8), 0, stream>>>(WV, WVt, HD, HD);
  castT<<<dim3(32, 32), dim3(32, 8), 0, stream>>>(lastW, lastWT, DIMD, 1000);
  // Mt[j][i] = sum_k WK[j][k]*WQ[i][k]  (= (WQ @ WK^T)^T)
  gemm_mfma<<<dim3(8, 8, 1), blk, 0, stream>>>(
      WKb, DIMD, ZR, WQb, DIMD, ZR, DIMD, 1,
      nullptr, Mt, DIMD, ZR, nullptr, nullptr, ZR, 1.f, DIMD, DIMD);

  // patch embed
  patchify_ln<<<TOKENS, blk, 0, stream>>>(image, ln1_g, ln1_b, Xp);
  gemm_mfma<<<dim3(8, 98, 1), blk, 0, stream>>>(
      Xp, PD, ZR, WembT, PD, ZR, PD, 0,
      xn, nullptr, DIMD, ZR, b_emb, nullptr, ZR, 1.f, TOKENS, DIMD);
  ln_rows2<<<TOKENS, blk, 0, stream>>>(xn, ln2_g, ln2_b, pos, x, nullptr);

  for (int l = 0; l < DEPTH; l++) {
    // xnb = bf16(LN(x))
    ln_rows2<<<TOKENS, blk, 0, stream>>>(x, norm_g, norm_b, nullptr, nullptr, (ushort4*)xnb);
    // xm = xnb @ M  (replaces separate Q and K projections)
    gemm_mfma<<<dim3(8, 98, 1), blk, 0, stream>>>(
        xnb, DIMD, ZR, Mt, DIMD, ZR, DIMD, 1,
        nullptr, xm, DIMD, ZR, nullptr, nullptr, ZR, 1.f, TOKENS, DIMD);
    // logits = xm @ xnb^T * scale
    gemm_qkt<<<dim3(4, 4, BATCH), blk, 0, stream>>>(xm, xnb, logits, scale);
    softmax_pad<<<BATCH*APAD_R, blk, 0, stream>>>(logits, Apad);
    // Gnat[t][h*128+e] = sum_d xnb[t][h*128+d] * WV[d][e]   (overwrites xm slab)
    gemm_mfma<<<dim3(1, 98, HEADS), blk, 0, stream>>>(
        xnb, DIMD, (long)HD, WVt, HD, ZR, HD, 1,
        nullptr, Gnat, DIMD, (long)HD, nullptr, nullptr, ZR, 1.f, TOKENS, HD);
    transposeG<<<dim3(16, 4, BATCH), dim3(32, 8), 0, stream>>>(Gnat, Gt);
    // x = A @ G + xnb (bf16 residual)
    gemm_mfma<<<dim3(8, 2, BATCH), blk, 0, stream>>>(
        Apad, APAD_C, (long)APAD_R*APAD_C, Gt, APAD_C, (long)DIMD*APAD_C, APAD_C, 0,
        x, nullptr, DIMD, (long)NTOK*DIMD, nullptr, xnb, (long)NTOK*DIMD, 1.f, NTOK, DIMD);
  }

  // classifier
  mean_tokens<<<dim3(BATCH, 4), blk, 0, stream>>>(x, meanxb);
  gemm_cls<<<dim3(8, 8), blk, 0, stream>>>(meanxb, lastWT, clsPart);
  cls_reduce<<<250, blk, 0, stream>>>(clsPart, lastb, out);
}

// Round 8
// 1450.005 us; speedup vs baseline: 6.4567x; 1.0575x over previous
//
#include <hip/hip_runtime.h>
#include <hip/hip_bf16.h>
#include <math.h>

#define NTOK   196
#define BATCH  64
#define TOKENS (BATCH*NTOK)   // 12544
#define DIMD   1024
#define PD     768
#define HEADS  8
#define HD     128
#define DEPTH  6
#define LN_EPS 1e-5f
#define APAD_R 256            // padded A rows per batch (for 128-tiles)
#define APAD_C 224            // padded K dim for A@G (7*32)

typedef __hip_bfloat16 bf16;
typedef __attribute__((ext_vector_type(8))) short bf16x8;
typedef __attribute__((ext_vector_type(4))) float f32x4;

typedef const __attribute__((address_space(1))) void* gptr_t;
typedef __attribute__((address_space(3))) void* lptr_t;

__device__ __forceinline__ void gl_lds16(const bf16* g, bf16* l) {
  __builtin_amdgcn_global_load_lds((gptr_t)(const void*)g, (lptr_t)(void*)l, 16, 0, 0);
}
__device__ __forceinline__ unsigned short bfbits(float f) {
  bf16 h = __float2bfloat16(f);
  return *(unsigned short*)&h;
}

// ================= generic MFMA GEMM: C[m][n] = sum_k A[m][k] * Bt[n][k] =================
// 128x128 tile, BK=32. mode 0: Cf = acc*alpha (+bias)(+bf16 res); mode 1: Cb = bf16(acc)
__global__ __launch_bounds__(256) void gemm_mfma(
    const bf16* __restrict__ A, int lda, long aStride,
    const bf16* __restrict__ Bt, int ldb, long bStride,
    int K, int mode,
    float* __restrict__ Cf, bf16* __restrict__ Cb, int ldc, long cStride,
    const float* __restrict__ bias, const bf16* __restrict__ resb, long resStride,
    float alpha, int Mb, int Nb) {
  __shared__ __align__(16) bf16 As[128*32];
  __shared__ __align__(16) bf16 Bs[128*32];
  const int z = blockIdx.z;
  A  += (long)z*aStride;
  Bt += (long)z*bStride;
  const int m0 = blockIdx.y*128, n0 = blockIdx.x*128;
  const int tid = threadIdx.x, lane = tid & 63, wv = tid >> 6;
  const int lrow = lane >> 2, lchunk = lane & 3;
  const bf16* ga = A + (long)(m0 + wv*32 + lrow)*lda + lchunk*8;
  const bf16* gb = Bt + (long)(n0 + wv*32 + lrow)*ldb + lchunk*8;
  bf16* lA = As + (wv*32)*32;
  bf16* lB = Bs + (wv*32)*32;
  const int mBase = (wv & 1)*64, nBase = (wv >> 1)*64;
  const int fr = lane & 15, fq = lane >> 4;

  f32x4 acc[4][4];
  #pragma unroll
  for (int i = 0; i < 4; i++)
    #pragma unroll
    for (int j = 0; j < 4; j++) acc[i][j] = (f32x4){0.f,0.f,0.f,0.f};

  for (int k0 = 0; k0 < K; k0 += 32) {
    gl_lds16(ga + k0,            lA);
    gl_lds16(ga + k0 + 16*lda,   lA + 16*32);
    gl_lds16(gb + k0,            lB);
    gl_lds16(gb + k0 + 16*ldb,   lB + 16*32);
    asm volatile("s_waitcnt vmcnt(0)" ::: "memory");
    __syncthreads();
    bf16x8 af[4], bfr[4];
    #pragma unroll
    for (int mi = 0; mi < 4; mi++)
      af[mi] = *(const bf16x8*)(As + (mBase + mi*16 + fr)*32 + fq*8);
    #pragma unroll
    for (int ni = 0; ni < 4; ni++)
      bfr[ni] = *(const bf16x8*)(Bs + (nBase + ni*16 + fr)*32 + fq*8);
    #pragma unroll
    for (int mi = 0; mi < 4; mi++)
      #pragma unroll
      for (int ni = 0; ni < 4; ni++)
        acc[mi][ni] = __builtin_amdgcn_mfma_f32_16x16x32_bf16(af[mi], bfr[ni], acc[mi][ni], 0, 0, 0);
    __syncthreads();
  }

  #pragma unroll
  for (int mi = 0; mi < 4; mi++)
    #pragma unroll
    for (int ni = 0; ni < 4; ni++)
      #pragma unroll
      for (int r = 0; r < 4; r++) {
        int gm = m0 + mBase + mi*16 + fq*4 + r;
        int gn = n0 + nBase + ni*16 + fr;
        if (gm >= Mb || gn >= Nb) continue;
        float v = acc[mi][ni][r] * alpha;
        if (mode == 0) {
          if (bias) v += bias[gn];
          if (resb) v += __bfloat162float(resb[(long)z*resStride + (long)gm*ldc + gn]);
          Cf[(long)z*cStride + (long)gm*ldc + gn] = v;
        } else {
          Cb[(long)z*cStride + (long)gm*ldc + gn] = __float2bfloat16(v);
        }
      }
}

// ================= QKT': logits[z] = xm[z] @ xnb[z]^T * scale, 64x64 tiles, lda/ldb 1024 =====
__global__ __launch_bounds__(256) void gemm_qkt(
    const bf16* __restrict__ Aq, const bf16* __restrict__ Bk,
    float* __restrict__ logits, float scale) {
  __shared__ __align__(16) bf16 As[64*32];
  __shared__ __align__(16) bf16 Bs[64*32];
  const int z = blockIdx.z;
  const bf16* A  = Aq + (long)z*NTOK*DIMD;
  const bf16* Bt = Bk + (long)z*NTOK*DIMD;
  const int m0 = blockIdx.y*64, n0 = blockIdx.x*64;
  const int tid = threadIdx.x, lane = tid & 63, wv = tid >> 6;
  const int lrow = lane >> 2, lchunk = lane & 3;
  const bf16* ga = A  + (long)(m0 + wv*16 + lrow)*DIMD + lchunk*8;
  const bf16* gb = Bt + (long)(n0 + wv*16 + lrow)*DIMD + lchunk*8;
  bf16* lA = As + (wv*16)*32;
  bf16* lB = Bs + (wv*16)*32;
  const int mBase = (wv & 1)*32, nBase = (wv >> 1)*32;
  const int fr = lane & 15, fq = lane >> 4;

  f32x4 acc[2][2];
  #pragma unroll
  for (int i = 0; i < 2; i++)
    #pragma unroll
    for (int j = 0; j < 2; j++) acc[i][j] = (f32x4){0.f,0.f,0.f,0.f};

  for (int k0 = 0; k0 < 1024; k0 += 32) {
    gl_lds16(ga + k0, lA);
    gl_lds16(gb + k0, lB);
    asm volatile("s_waitcnt vmcnt(0)" ::: "memory");
    __syncthreads();
    bf16x8 af[2], bfr[2];
    #pragma unroll
    for (int mi = 0; mi < 2; mi++)
      af[mi] = *(const bf16x8*)(As + (mBase + mi*16 + fr)*32 + fq*8);
    #pragma unroll
    for (int ni = 0; ni < 2; ni++)
      bfr[ni] = *(const bf16x8*)(Bs + (nBase + ni*16 + fr)*32 + fq*8);
    #pragma unroll
    for (int mi = 0; mi < 2; mi++)
      #pragma unroll
      for (int ni = 0; ni < 2; ni++)
        acc[mi][ni] = __builtin_amdgcn_mfma_f32_16x16x32_bf16(af[mi], bfr[ni], acc[mi][ni], 0, 0, 0);
    __syncthreads();
  }

  #pragma unroll
  for (int mi = 0; mi < 2; mi++)
    #pragma unroll
    for (int ni = 0; ni < 2; ni++)
      #pragma unroll
      for (int r = 0; r < 4; r++) {
        int gm = m0 + mBase + mi*16 + fq*4 + r;
        int gn = n0 + nBase + ni*16 + fr;
        if (gm < NTOK && gn < NTOK)
          logits[(long)z*NTOK*NTOK + (long)gm*NTOK + gn] = acc[mi][ni][r] * scale;
      }
}

// ====== V-GEMM direct-Gt: Gt[z][h*128+d][t] = sum_e WVt[d][e]*xnb[z*196+t][h*128+e] ======
__global__ __launch_bounds__(256) void gemm_v(
    const bf16* __restrict__ WVt, const bf16* __restrict__ xnb, bf16* __restrict__ Gt) {
  __shared__ __align__(16) bf16 As[128*32];
  __shared__ __align__(16) bf16 Bs[128*32];
  const int z = blockIdx.z, h = blockIdx.y, n0 = blockIdx.x*128;
  const int tid = threadIdx.x, lane = tid & 63, wv = tid >> 6;
  const int lrow = lane >> 2, lchunk = lane & 3;
  const bf16* ga = WVt + (long)(wv*32 + lrow)*HD + lchunk*8;
  const bf16* gb = xnb + (long)(z*NTOK + n0 + wv*32 + lrow)*DIMD + h*HD + lchunk*8;
  bf16* lA = As + (wv*32)*32;
  bf16* lB = Bs + (wv*32)*32;
  const int mBase = (wv & 1)*64, nBase = (wv >> 1)*64;
  const int fr = lane & 15, fq = lane >> 4;

  f32x4 acc[4][4];
  #pragma unroll
  for (int i = 0; i < 4; i++)
    #pragma unroll
    for (int j = 0; j < 4; j++) acc[i][j] = (f32x4){0.f,0.f,0.f,0.f};

  for (int k0 = 0; k0 < HD; k0 += 32) {
    gl_lds16(ga + k0,           lA);
    gl_lds16(ga + k0 + 16*HD,   lA + 16*32);
    gl_lds16(gb + k0,           lB);
    gl_lds16(gb + k0 + 16*DIMD, lB + 16*32);
    asm volatile("s_waitcnt vmcnt(0)" ::: "memory");
    __syncthreads();
    bf16x8 af[4], bfr[4];
    #pragma unroll
    for (int mi = 0; mi < 4; mi++)
      af[mi] = *(const bf16x8*)(As + (mBase + mi*16 + fr)*32 + fq*8);
    #pragma unroll
    for (int ni = 0; ni < 4; ni++)
      bfr[ni] = *(const bf16x8*)(Bs + (nBase + ni*16 + fr)*32 + fq*8);
    #pragma unroll
    for (int mi = 0; mi < 4; mi++)
      #pragma unroll
      for (int ni = 0; ni < 4; ni++)
        acc[mi][ni] = __builtin_amdgcn_mfma_f32_16x16x32_bf16(af[mi], bfr[ni], acc[mi][ni], 0, 0, 0);
    __syncthreads();
  }

  #pragma unroll
  for (int mi = 0; mi < 4; mi++)
    #pragma unroll
    for (int ni = 0; ni < 4; ni++)
      #pragma unroll
      for (int r = 0; r < 4; r++) {
        int gm = mBase + mi*16 + fq*4 + r;          // output dim within head (0..127)
        int gn = n0 + nBase + ni*16 + fr;           // token
        if (gn < NTOK)
          Gt[((long)z*DIMD + h*HD + gm)*APAD_C + gn] = __float2bfloat16(acc[mi][ni][r]);
        else if (gn < APAD_C)
          Gt[((long)z*DIMD + h*HD + gm)*APAD_C + gn] = __float2bfloat16(0.f);
      }
}

// ================= classifier split-K =================
__global__ __launch_bounds__(256) void gemm_cls(
    const bf16* __restrict__ A, const bf16* __restrict__ Bt,
    float* __restrict__ Cp) {
  __shared__ __align__(16) bf16 As[64*32];
  __shared__ __align__(16) bf16 Bs[128*32];
  const int n0 = blockIdx.x*128, kz = blockIdx.y;
  const int tid = threadIdx.x, lane = tid & 63, wv = tid >> 6;
  const bf16* ga = A + (tid>>2)*DIMD + kz*128 + (tid&3)*8;
  const bf16* gb = Bt + (long)(n0 + wv*32 + (lane>>2))*DIMD + kz*128 + (lane&3)*8;
  bf16* lA = As + wv*512;
  bf16* lB = Bs + (wv*32)*32;
  const int fr = lane & 15, fq = lane >> 4;
  f32x4 acc[4][2];
  #pragma unroll
  for (int i = 0; i < 4; i++)
    #pragma unroll
    for (int j = 0; j < 2; j++) acc[i][j] = (f32x4){0.f,0.f,0.f,0.f};
  for (int it = 0; it < 4; it++) {
    gl_lds16(ga + it*32, lA);
    gl_lds16(gb + it*32,            lB);
    gl_lds16(gb + it*32 + 16*DIMD,  lB + 16*32);
    asm volatile("s_waitcnt vmcnt(0)" ::: "memory");
    __syncthreads();
    bf16x8 af[4], bfr[2];
    #pragma unroll
    for (int mi = 0; mi < 4; mi++)
      af[mi] = *(const bf16x8*)(As + (mi*16 + fr)*32 + fq*8);
    #pragma unroll
    for (int ni = 0; ni < 2; ni++)
      bfr[ni] = *(const bf16x8*)(Bs + (wv*32 + ni*16 + fr)*32 + fq*8);
    #pragma unroll
    for (int mi = 0; mi < 4; mi++)
      #pragma unroll
      for (int ni = 0; ni < 2; ni++)
        acc[mi][ni] = __builtin_amdgcn_mfma_f32_16x16x32_bf16(af[mi], bfr[ni], acc[mi][ni], 0, 0, 0);
    __syncthreads();
  }
  #pragma unroll
  for (int mi = 0; mi < 4; mi++)
    #pragma unroll
    for (int ni = 0; ni < 2; ni++)
      #pragma unroll
      for (int r = 0; r < 4; r++) {
        int gm = mi*16 + fq*4 + r;
        int gn = n0 + wv*32 + ni*16 + fr;
        Cp[((long)kz*64 + gm)*DIMD + gn] = acc[mi][ni][r];
      }
}

__global__ __launch_bounds__(256) void cls_reduce(
    const float* __restrict__ Cp, const float* __restrict__ bias,
    float* __restrict__ out) {
  int i = blockIdx.x*256 + threadIdx.x;
  int m = i / 1000, n = i - m*1000;
  float s = bias[n];
  #pragma unroll
  for (int kz = 0; kz < 8; kz++) s += Cp[((long)kz*64 + m)*DIMD + n];
  out[i] = s;
}

// ================= patchify + LN1 (dim 768) -> bf16 =================
__global__ __launch_bounds__(256) void patchify_ln(
    const float* __restrict__ img, const float* __restrict__ g,
    const float* __restrict__ b, bf16* __restrict__ out) {
  int t = blockIdx.x;
  int bi = t / NTOK, n = t % NTOK;
  int ph = n / 14, pw = n % 14;
  __shared__ float vals[PD];
  __shared__ float red[256];
  int tid = threadIdx.x;
  for (int j = tid; j < PD; j += 256) {
    int p1 = j / 48, rem = j % 48, p2 = rem / 3, c = rem % 3;
    vals[j] = img[(((long)bi*3 + c)*224 + (ph*16 + p1))*224 + (pw*16 + p2)];
  }
  __syncthreads();
  float s = 0.f;
  for (int j = tid; j < PD; j += 256) s += vals[j];
  red[tid] = s; __syncthreads();
  for (int st = 128; st > 0; st >>= 1) { if (tid < st) red[tid] += red[tid+st]; __syncthreads(); }
  float mean = red[0] / (float)PD;
  __syncthreads();
  float s2 = 0.f;
  for (int j = tid; j < PD; j += 256) { float d = vals[j]-mean; s2 += d*d; }
  red[tid] = s2; __syncthreads();
  for (int st = 128; st > 0; st >>= 1) { if (tid < st) red[tid] += red[tid+st]; __syncthreads(); }
  float rstd = rsqrtf(red[0]/(float)PD + LN_EPS);
  for (int j = tid; j < PD; j += 256)
    out[(long)t*PD + j] = __float2bfloat16((vals[j]-mean)*rstd*g[j] + b[j]);
}

// ================= LayerNorm rows (dim=1024): optional fp32 out, optional bf16 out =================
__global__ __launch_bounds__(256) void ln_rows2(
    const float* __restrict__ in, const float* __restrict__ g,
    const float* __restrict__ b, const float* __restrict__ pos,
    float* __restrict__ outf, ushort4* __restrict__ outb) {
  long t = blockIdx.x;
  int tid = threadIdx.x;
  float4 v = ((const float4*)(in + t*DIMD))[tid];
  float s  = v.x+v.y+v.z+v.w;
  float s2 = v.x*v.x+v.y*v.y+v.z*v.z+v.w*v.w;
  __shared__ float rs[256], rq[256];
  rs[tid]=s; rq[tid]=s2; __syncthreads();
  for (int st = 128; st > 0; st >>= 1) {
    if (tid < st) { rs[tid]+=rs[tid+st]; rq[tid]+=rq[tid+st]; }
    __syncthreads();
  }
  float mean = rs[0]*(1.f/1024.f);
  float var  = rq[0]*(1.f/1024.f) - mean*mean;
  float rstd = rsqrtf(var + LN_EPS);
  float4 gg = ((const float4*)g)[tid];
  float4 bb = ((const float4*)b)[tid];
  float4 o;
  o.x = (v.x-mean)*rstd*gg.x + bb.x;
  o.y = (v.y-mean)*rstd*gg.y + bb.y;
  o.z = (v.z-mean)*rstd*gg.z + bb.z;
  o.w = (v.w-mean)*rstd*gg.w + bb.w;
  if (pos) {
    float4 pp = ((const float4*)(pos + (long)(t % NTOK)*DIMD))[tid];
    o.x += pp.x; o.y += pp.y; o.z += pp.z; o.w += pp.w;
  }
  if (outf) ((float4*)(outf + t*DIMD))[tid] = o;
  if (outb) {
    ushort4 u;
    u.x = bfbits(o.x); u.y = bfbits(o.y); u.z = bfbits(o.z); u.w = bfbits(o.w);
    outb[t*256 + tid] = u;
  }
}

// ================= cast + transpose weights: fp32 [R][C] -> bf16 [C][R] =================
__global__ void castT(const float* __restrict__ src, bf16* __restrict__ dst, int R, int C) {
  __shared__ float t[32][33];
  int rb = blockIdx.y*32, cb = blockIdx.x*32;
  int tx = threadIdx.x, ty = threadIdx.y;  // (32,8)
  for (int i = ty; i < 32; i += 8)
    if (rb+i < R && cb+tx < C) t[i][tx] = src[(long)(rb+i)*C + cb+tx];
  __syncthreads();
  for (int i = ty; i < 32; i += 8)
    if (cb+i < C && rb+tx < R) dst[(long)(cb+i)*R + rb+tx] = __float2bfloat16(t[tx][i]);
}

// ================= natural cast fp32 -> bf16 (elementwise, float4) =================
__global__ __launch_bounds__(256) void castN(
    const float* __restrict__ src, ushort4* __restrict__ dst) {
  int i = blockIdx.x*256 + threadIdx.x;
  float4 v = ((const float4*)src)[i];
  ushort4 u;
  u.x = bfbits(v.x); u.y = bfbits(v.y); u.z = bfbits(v.z); u.w = bfbits(v.w);
  dst[i] = u;
}

// ================= softmax over 196 logits -> bf16 A padded to 256x224 (pads zeroed) =====
__global__ __launch_bounds__(256) void softmax_pad(
    const float* __restrict__ logits, bf16* __restrict__ Apad) {
  int r = blockIdx.x;              // 0..BATCH*256-1
  int z = r >> 8, rq = r & 255;
  int tid = threadIdx.x;
  if (rq >= NTOK) {                // zero pad rows 196..255
    if (tid < APAD_C)
      Apad[((long)z*APAD_R + rq)*APAD_C + tid] = __float2bfloat16(0.f);
    return;
  }
  const float* row = logits + ((long)z*NTOK + rq)*NTOK;
  __shared__ float red[256];
  float v = (tid < NTOK) ? row[tid] : -INFINITY;
  red[tid] = v; __syncthreads();
  for (int st = 128; st > 0; st >>= 1) { if (tid < st) red[tid] = fmaxf(red[tid], red[tid+st]); __syncthreads(); }
  float mx = red[0]; __syncthreads();
  float e = (tid < NTOK) ? __expf(v - mx) : 0.f;
  red[tid] = e; __syncthreads();
  for (int st = 128; st > 0; st >>= 1) { if (tid < st) red[tid] += red[tid+st]; __syncthreads(); }
  float inv = 1.f / red[0];
  if (tid < APAD_C)
    Apad[((long)z*APAD_R + rq)*APAD_C + tid] = __float2bfloat16(tid < NTOK ? e*inv : 0.f);
}

// ================= mean over tokens -> bf16 =================
__global__ __launch_bounds__(256) void mean_tokens(
    const float* __restrict__ x, bf16* __restrict__ outb) {
  int b = blockIdx.x;
  int d = blockIdx.y*256 + threadIdx.x;
  const float* p = x + (long)b*NTOK*DIMD + d;
  float s = 0.f;
  #pragma unroll 4
  for (int n = 0; n < NTOK; n++) s += p[(long)n*DIMD];
  outb[(long)b*DIMD + d] = __float2bfloat16(s * (1.f/196.f));
}

extern "C" void kernel_launch(void* const* d_in, const int* in_sizes, int n_in,
                              void* d_out, int out_size, void* d_ws, size_t ws_size,
                              hipStream_t stream) {
  (void)in_sizes; (void)n_in; (void)out_size; (void)ws_size;
  const float* image = (const float*)d_in[0];
  const float* ln1_g = (const float*)d_in[1];
  const float* ln1_b = (const float*)d_in[2];
  const float* W_emb = (const float*)d_in[3];
  const float* b_emb = (const float*)d_in[4];
  const float* ln2_g = (const float*)d_in[5];
  const float* ln2_b = (const float*)d_in[6];
  const float* pos   = (const float*)d_in[7];
  const float* norm_g= (const float*)d_in[8];
  const float* norm_b= (const float*)d_in[9];
  const float* WV    = (const float*)d_in[10];
  const float* WK    = (const float*)d_in[11];
  const float* WQ    = (const float*)d_in[12];
  const float* lastW = (const float*)d_in[13];
  const float* lastb = (const float*)d_in[14];
  float* out = (float*)d_out;

  char* W = (char*)d_ws;
  float* x     = (float*)(W);                      // 51,380,224
  bf16*  xnb   = (bf16*) (W + 51380224);           // 25,690,112
  bf16*  xm    = (bf16*) (W + 77070336);           // 25.7MB in 51.6MB slab (alias Xp; overread zone)
  bf16*  Xp    = xm;
  // slabB: embed-phase xn (fp32 51.4 MB) OR layer-phase Gt+logits+Apad
  float* xn    = (float*)(W + 128712704);
  bf16*  Gt    = (bf16*) (W + 128712704);          // 29,360,128
  float* logits= (float*)(W + 158072832);          //  9,834,496
  bf16*  Apad  = (bf16*) (W + 167907328);          //  7,340,032
  bf16*  WembT = (bf16*) (W + 180092928);          //  1,572,864
  bf16*  WQb   = (bf16*) (W + 181665792);          //  2,097,152 (natural layout)
  bf16*  WKb   = (bf16*) (W + 183762944);          //  2,097,152 (natural layout)
  bf16*  WVt   = (bf16*) (W + 185860096);          //     32,768
  bf16*  lastWT= (bf16*) (W + 185892864);          //  2,097,152
  bf16*  meanxb= (bf16*) (W + 187990016);          //    131,072
  float* clsPart=(float*)(W + 188121088);          //  2,097,152
  bf16*  Mt    = (bf16*) (W + 190218240);          //  2,097,152 (M^T = WK @ WQ^T)

  dim3 blk(256);
  const float scale = 0.08838834764831845f;  // 128^-0.5
  const long ZR = 0;

  // weight casts
  castT<<<dim3(32, 24), dim3(32, 8), 0, stream>>>(W_emb, WembT, PD, DIMD);
  castN<<<1024, blk, 0, stream>>>(WQ, (ushort4*)WQb);
  castN<<<1024, blk, 0, stream>>>(WK, (ushort4*)WKb);
  castT<<<dim3(4, 4),  dim3(32, 8), 0, stream>>>(WV, WVt, HD, HD);
  castT<<<dim3(32, 32), dim3(32, 8), 0, stream>>>(lastW, lastWT, DIMD, 1000);
  // Mt[j][i] = sum_k WK[j][k]*WQ[i][k]  (= (WQ @ WK^T)^T)
  gemm_mfma<<<dim3(8, 8, 1), blk, 0, stream>>>(
      WKb, DIMD, ZR, WQb, DIMD, ZR, DIMD, 1,
      nullptr, Mt, DIMD, ZR, nullptr, nullptr, ZR, 1.f, DIMD, DIMD);

  // patch embed
  patchify_ln<<<TOKENS, blk, 0, stream>>>(image, ln1_g, ln1_b, Xp);
  gemm_mfma<<<dim3(8, 98, 1), blk, 0, stream>>>(
      Xp, PD, ZR, WembT, PD, ZR, PD, 0,
      xn, nullptr, DIMD, ZR, b_emb, nullptr, ZR, 1.f, TOKENS, DIMD);
  ln_rows2<<<TOKENS, blk, 0, stream>>>(xn, ln2_g, ln2_b, pos, x, nullptr);

  for (int l = 0; l < DEPTH; l++) {
    // xnb = bf16(LN(x))
    ln_rows2<<<TOKENS, blk, 0, stream>>>(x, norm_g, norm_b, nullptr, nullptr, (ushort4*)xnb);
    // xm = xnb @ M
    gemm_mfma<<<dim3(8, 98, 1), blk, 0, stream>>>(
        xnb, DIMD, ZR, Mt, DIMD, ZR, DIMD, 1,
        nullptr, xm, DIMD, ZR, nullptr, nullptr, ZR, 1.f, TOKENS, DIMD);
    // logits = xm @ xnb^T * scale
    gemm_qkt<<<dim3(4, 4, BATCH), blk, 0, stream>>>(xm, xnb, logits, scale);
    softmax_pad<<<BATCH*APAD_R, blk, 0, stream>>>(logits, Apad);
    // Gt[b][dim][tok] = WV^T @ xn^T  (direct transposed layout, pad cols zeroed)
    gemm_v<<<dim3(2, HEADS, BATCH), blk, 0, stream>>>(WVt, xnb, Gt);
    // x = Apad @ G + xnb (bf16 residual)
    gemm_mfma<<<dim3(8, 2, BATCH), blk, 0, stream>>>(
        Apad, APAD_C, (long)APAD_R*APAD_C, Gt, APAD_C, (long)DIMD*APAD_C, APAD_C, 0,
        x, nullptr, DIMD, (long)NTOK*DIMD, nullptr, xnb, (long)NTOK*DIMD, 1.f, NTOK, DIMD);
  }

  // classifier
  mean_tokens<<<dim3(BATCH, 4), blk, 0, stream>>>(x, meanxb);
  gemm_cls<<<dim3(8, 8), blk, 0, stream>>>(meanxb, lastWT, clsPart);
  cls_reduce<<<250, blk, 0, stream>>>(clsPart, lastb, out);
}

// Round 9
// 1367.969 us; speedup vs baseline: 6.8440x; 1.0600x over previous
//
#include <hip/hip_runtime.h>
#include <hip/hip_bf16.h>
#include <math.h>

#define NTOK   196
#define BATCH  64
#define TOKENS (BATCH*NTOK)   // 12544
#define DIMD   1024
#define PD     768
#define HEADS  8
#define HD     128
#define DEPTH  6
#define LN_EPS 1e-5f
#define APAD_R 256            // padded A rows per batch (for 128-tiles)
#define APAD_C 224            // padded K dim for A@G (7*32)

typedef __hip_bfloat16 bf16;
typedef __attribute__((ext_vector_type(8))) short bf16x8;
typedef __attribute__((ext_vector_type(4))) float f32x4;

typedef const __attribute__((address_space(1))) void* gptr_t;
typedef __attribute__((address_space(3))) void* lptr_t;

__device__ __forceinline__ void gl_lds16(const bf16* g, bf16* l) {
  __builtin_amdgcn_global_load_lds((gptr_t)(const void*)g, (lptr_t)(void*)l, 16, 0, 0);
}
__device__ __forceinline__ unsigned short bfbits(float f) {
  bf16 h = __float2bfloat16(f);
  return *(unsigned short*)&h;
}

// ================= generic MFMA GEMM: C[m][n] = sum_k A[m][k] * Bt[n][k] =================
// 128x128 tile, BK=32. mode 0: Cf = acc*alpha (+bias)(+bf16 res); mode 1: Cb = bf16(acc)
__global__ __launch_bounds__(256) void gemm_mfma(
    const bf16* __restrict__ A, int lda, long aStride,
    const bf16* __restrict__ Bt, int ldb, long bStride,
    int K, int mode,
    float* __restrict__ Cf, bf16* __restrict__ Cb, int ldc, long cStride,
    const float* __restrict__ bias, const bf16* __restrict__ resb, long resStride,
    float alpha, int Mb, int Nb) {
  __shared__ __align__(16) bf16 As[128*32];
  __shared__ __align__(16) bf16 Bs[128*32];
  const int z = blockIdx.z;
  A  += (long)z*aStride;
  Bt += (long)z*bStride;
  const int m0 = blockIdx.y*128, n0 = blockIdx.x*128;
  const int tid = threadIdx.x, lane = tid & 63, wv = tid >> 6;
  const int lrow = lane >> 2, lchunk = lane & 3;
  const bf16* ga = A + (long)(m0 + wv*32 + lrow)*lda + lchunk*8;
  const bf16* gb = Bt + (long)(n0 + wv*32 + lrow)*ldb + lchunk*8;
  bf16* lA = As + (wv*32)*32;
  bf16* lB = Bs + (wv*32)*32;
  const int mBase = (wv & 1)*64, nBase = (wv >> 1)*64;
  const int fr = lane & 15, fq = lane >> 4;

  f32x4 acc[4][4];
  #pragma unroll
  for (int i = 0; i < 4; i++)
    #pragma unroll
    for (int j = 0; j < 4; j++) acc[i][j] = (f32x4){0.f,0.f,0.f,0.f};

  for (int k0 = 0; k0 < K; k0 += 32) {
    gl_lds16(ga + k0,            lA);
    gl_lds16(ga + k0 + 16*lda,   lA + 16*32);
    gl_lds16(gb + k0,            lB);
    gl_lds16(gb + k0 + 16*ldb,   lB + 16*32);
    asm volatile("s_waitcnt vmcnt(0)" ::: "memory");
    __syncthreads();
    bf16x8 af[4], bfr[4];
    #pragma unroll
    for (int mi = 0; mi < 4; mi++)
      af[mi] = *(const bf16x8*)(As + (mBase + mi*16 + fr)*32 + fq*8);
    #pragma unroll
    for (int ni = 0; ni < 4; ni++)
      bfr[ni] = *(const bf16x8*)(Bs + (nBase + ni*16 + fr)*32 + fq*8);
    #pragma unroll
    for (int mi = 0; mi < 4; mi++)
      #pragma unroll
      for (int ni = 0; ni < 4; ni++)
        acc[mi][ni] = __builtin_amdgcn_mfma_f32_16x16x32_bf16(af[mi], bfr[ni], acc[mi][ni], 0, 0, 0);
    __syncthreads();
  }

  #pragma unroll
  for (int mi = 0; mi < 4; mi++)
    #pragma unroll
    for (int ni = 0; ni < 4; ni++)
      #pragma unroll
      for (int r = 0; r < 4; r++) {
        int gm = m0 + mBase + mi*16 + fq*4 + r;
        int gn = n0 + nBase + ni*16 + fr;
        if (gm >= Mb || gn >= Nb) continue;
        float v = acc[mi][ni][r] * alpha;
        if (mode == 0) {
          if (bias) v += bias[gn];
          if (resb) v += __bfloat162float(resb[(long)z*resStride + (long)gm*ldc + gn]);
          Cf[(long)z*cStride + (long)gm*ldc + gn] = v;
        } else {
          Cb[(long)z*cStride + (long)gm*ldc + gn] = __float2bfloat16(v);
        }
      }
}

// ====== fused QKT+softmax: per batch z, 64-row tile x full 224-col width ======
// logits = xm[z] @ xnb[z]^T (fp32 acc), row-softmax with max-sub (identical math to
// softmax_pad), writes bf16 Apad with pad rows (>=196) and pad cols (>=196) zeroed.
__global__ __launch_bounds__(256) void gemm_qs(
    const bf16* __restrict__ xmp, const bf16* __restrict__ xnbp,
    bf16* __restrict__ Apad, float scale) {
  __shared__ __align__(16) bf16 As[64*32];
  __shared__ __align__(16) bf16 Bs[224*32];
  const int z = blockIdx.z;
  const int y0 = blockIdx.y*64;                 // 0,64,128,192
  const bf16* A  = xmp  + (long)z*NTOK*DIMD;
  const bf16* Bt = xnbp + (long)z*NTOK*DIMD;
  const int tid = threadIdx.x, lane = tid & 63, wv = tid >> 6;
  const int lrow = lane >> 2, lchunk = lane & 3;
  // A staging: wave wv stages its own 16 rows
  const bf16* ga = A + (long)(y0 + wv*16 + lrow)*DIMD + lchunk*8;
  bf16* lA = As + (wv*16)*32;
  // B staging: waves 0..2 stage 64 rows each, wave 3 stages 32 rows (224 total)
  const bf16* gb = Bt + (long)(wv*64 + lrow)*DIMD + lchunk*8;
  bf16* lB = Bs + (wv*64)*32;
  const int nIss = (wv < 3) ? 4 : 2;
  const int fr = lane & 15, fq = lane >> 4;

  f32x4 acc[14];
  #pragma unroll
  for (int j = 0; j < 14; j++) acc[j] = (f32x4){0.f,0.f,0.f,0.f};

  for (int k0 = 0; k0 < 1024; k0 += 32) {
    gl_lds16(ga + k0, lA);
    for (int i = 0; i < nIss; i++)
      gl_lds16(gb + k0 + (long)i*16*DIMD, lB + i*16*32);
    asm volatile("s_waitcnt vmcnt(0)" ::: "memory");
    __syncthreads();
    bf16x8 af = *(const bf16x8*)(As + (wv*16 + fr)*32 + fq*8);
    #pragma unroll
    for (int j = 0; j < 14; j++) {
      bf16x8 bfr = *(const bf16x8*)(Bs + (j*16 + fr)*32 + fq*8);
      acc[j] = __builtin_amdgcn_mfma_f32_16x16x32_bf16(af, bfr, acc[j], 0, 0, 0);
    }
    __syncthreads();
  }

  // per-row softmax: row = y0 + wv*16 + fq*4 + r; cols j*16 + fr
  #pragma unroll
  for (int r = 0; r < 4; r++) {
    float mx = -INFINITY;
    #pragma unroll
    for (int j = 0; j < 14; j++) {
      int col = j*16 + fr;
      if (col < NTOK) mx = fmaxf(mx, acc[j][r]);
    }
    #pragma unroll
    for (int off = 1; off < 16; off <<= 1) mx = fmaxf(mx, __shfl_xor(mx, off));
    float e[14];
    float s = 0.f;
    #pragma unroll
    for (int j = 0; j < 14; j++) {
      int col = j*16 + fr;
      e[j] = (col < NTOK) ? __expf((acc[j][r] - mx) * scale) : 0.f;
      s += e[j];
    }
    #pragma unroll
    for (int off = 1; off < 16; off <<= 1) s += __shfl_xor(s, off);
    float inv = 1.f / s;
    int grow = y0 + wv*16 + fq*4 + r;
    bf16* dst = Apad + ((long)z*APAD_R + grow)*APAD_C;
    #pragma unroll
    for (int j = 0; j < 14; j++) {
      int col = j*16 + fr;
      float outv = (grow < NTOK) ? e[j]*inv : 0.f;   // col>=196 -> e=0 -> writes 0
      dst[col] = __float2bfloat16(outv);
    }
  }
}

// ====== V-GEMM direct-Gt: Gt[z][h*128+d][t] = sum_e WVt[d][e]*xnb[z*196+t][h*128+e] ======
__global__ __launch_bounds__(256) void gemm_v(
    const bf16* __restrict__ WVt, const bf16* __restrict__ xnb, bf16* __restrict__ Gt) {
  __shared__ __align__(16) bf16 As[128*32];
  __shared__ __align__(16) bf16 Bs[128*32];
  const int z = blockIdx.z, h = blockIdx.y, n0 = blockIdx.x*128;
  const int tid = threadIdx.x, lane = tid & 63, wv = tid >> 6;
  const int lrow = lane >> 2, lchunk = lane & 3;
  const bf16* ga = WVt + (long)(wv*32 + lrow)*HD + lchunk*8;
  const bf16* gb = xnb + (long)(z*NTOK + n0 + wv*32 + lrow)*DIMD + h*HD + lchunk*8;
  bf16* lA = As + (wv*32)*32;
  bf16* lB = Bs + (wv*32)*32;
  const int mBase = (wv & 1)*64, nBase = (wv >> 1)*64;
  const int fr = lane & 15, fq = lane >> 4;

  f32x4 acc[4][4];
  #pragma unroll
  for (int i = 0; i < 4; i++)
    #pragma unroll
    for (int j = 0; j < 4; j++) acc[i][j] = (f32x4){0.f,0.f,0.f,0.f};

  for (int k0 = 0; k0 < HD; k0 += 32) {
    gl_lds16(ga + k0,           lA);
    gl_lds16(ga + k0 + 16*HD,   lA + 16*32);
    gl_lds16(gb + k0,           lB);
    gl_lds16(gb + k0 + 16*DIMD, lB + 16*32);
    asm volatile("s_waitcnt vmcnt(0)" ::: "memory");
    __syncthreads();
    bf16x8 af[4], bfr[4];
    #pragma unroll
    for (int mi = 0; mi < 4; mi++)
      af[mi] = *(const bf16x8*)(As + (mBase + mi*16 + fr)*32 + fq*8);
    #pragma unroll
    for (int ni = 0; ni < 4; ni++)
      bfr[ni] = *(const bf16x8*)(Bs + (nBase + ni*16 + fr)*32 + fq*8);
    #pragma unroll
    for (int mi = 0; mi < 4; mi++)
      #pragma unroll
      for (int ni = 0; ni < 4; ni++)
        acc[mi][ni] = __builtin_amdgcn_mfma_f32_16x16x32_bf16(af[mi], bfr[ni], acc[mi][ni], 0, 0, 0);
    __syncthreads();
  }

  #pragma unroll
  for (int mi = 0; mi < 4; mi++)
    #pragma unroll
    for (int ni = 0; ni < 4; ni++)
      #pragma unroll
      for (int r = 0; r < 4; r++) {
        int gm = mBase + mi*16 + fq*4 + r;          // output dim within head (0..127)
        int gn = n0 + nBase + ni*16 + fr;           // token
        if (gn < NTOK)
          Gt[((long)z*DIMD + h*HD + gm)*APAD_C + gn] = __float2bfloat16(acc[mi][ni][r]);
        else if (gn < APAD_C)
          Gt[((long)z*DIMD + h*HD + gm)*APAD_C + gn] = __float2bfloat16(0.f);
      }
}

// ================= classifier split-K =================
__global__ __launch_bounds__(256) void gemm_cls(
    const bf16* __restrict__ A, const bf16* __restrict__ Bt,
    float* __restrict__ Cp) {
  __shared__ __align__(16) bf16 As[64*32];
  __shared__ __align__(16) bf16 Bs[128*32];
  const int n0 = blockIdx.x*128, kz = blockIdx.y;
  const int tid = threadIdx.x, lane = tid & 63, wv = tid >> 6;
  const bf16* ga = A + (tid>>2)*DIMD + kz*128 + (tid&3)*8;
  const bf16* gb = Bt + (long)(n0 + wv*32 + (lane>>2))*DIMD + kz*128 + (lane&3)*8;
  bf16* lA = As + wv*512;
  bf16* lB = Bs + (wv*32)*32;
  const int fr = lane & 15, fq = lane >> 4;
  f32x4 acc[4][2];
  #pragma unroll
  for (int i = 0; i < 4; i++)
    #pragma unroll
    for (int j = 0; j < 2; j++) acc[i][j] = (f32x4){0.f,0.f,0.f,0.f};
  for (int it = 0; it < 4; it++) {
    gl_lds16(ga + it*32, lA);
    gl_lds16(gb + it*32,            lB);
    gl_lds16(gb + it*32 + 16*DIMD,  lB + 16*32);
    asm volatile("s_waitcnt vmcnt(0)" ::: "memory");
    __syncthreads();
    bf16x8 af[4], bfr[2];
    #pragma unroll
    for (int mi = 0; mi < 4; mi++)
      af[mi] = *(const bf16x8*)(As + (mi*16 + fr)*32 + fq*8);
    #pragma unroll
    for (int ni = 0; ni < 2; ni++)
      bfr[ni] = *(const bf16x8*)(Bs + (wv*32 + ni*16 + fr)*32 + fq*8);
    #pragma unroll
    for (int mi = 0; mi < 4; mi++)
      #pragma unroll
      for (int ni = 0; ni < 2; ni++)
        acc[mi][ni] = __builtin_amdgcn_mfma_f32_16x16x32_bf16(af[mi], bfr[ni], acc[mi][ni], 0, 0, 0);
    __syncthreads();
  }
  #pragma unroll
  for (int mi = 0; mi < 4; mi++)
    #pragma unroll
    for (int ni = 0; ni < 2; ni++)
      #pragma unroll
      for (int r = 0; r < 4; r++) {
        int gm = mi*16 + fq*4 + r;
        int gn = n0 + wv*32 + ni*16 + fr;
        Cp[((long)kz*64 + gm)*DIMD + gn] = acc[mi][ni][r];
      }
}

__global__ __launch_bounds__(256) void cls_reduce(
    const float* __restrict__ Cp, const float* __restrict__ bias,
    float* __restrict__ out) {
  int i = blockIdx.x*256 + threadIdx.x;
  int m = i / 1000, n = i - m*1000;
  float s = bias[n];
  #pragma unroll
  for (int kz = 0; kz < 8; kz++) s += Cp[((long)kz*64 + m)*DIMD + n];
  out[i] = s;
}

// ================= patchify + LN1 (dim 768) -> bf16 =================
__global__ __launch_bounds__(256) void patchify_ln(
    const float* __restrict__ img, const float* __restrict__ g,
    const float* __restrict__ b, bf16* __restrict__ out) {
  int t = blockIdx.x;
  int bi = t / NTOK, n = t % NTOK;
  int ph = n / 14, pw = n % 14;
  __shared__ float vals[PD];
  __shared__ float red[256];
  int tid = threadIdx.x;
  for (int j = tid; j < PD; j += 256) {
    int p1 = j / 48, rem = j % 48, p2 = rem / 3, c = rem % 3;
    vals[j] = img[(((long)bi*3 + c)*224 + (ph*16 + p1))*224 + (pw*16 + p2)];
  }
  __syncthreads();
  float s = 0.f;
  for (int j = tid; j < PD; j += 256) s += vals[j];
  red[tid] = s; __syncthreads();
  for (int st = 128; st > 0; st >>= 1) { if (tid < st) red[tid] += red[tid+st]; __syncthreads(); }
  float mean = red[0] / (float)PD;
  __syncthreads();
  float s2 = 0.f;
  for (int j = tid; j < PD; j += 256) { float d = vals[j]-mean; s2 += d*d; }
  red[tid] = s2; __syncthreads();
  for (int st = 128; st > 0; st >>= 1) { if (tid < st) red[tid] += red[tid+st]; __syncthreads(); }
  float rstd = rsqrtf(red[0]/(float)PD + LN_EPS);
  for (int j = tid; j < PD; j += 256)
    out[(long)t*PD + j] = __float2bfloat16((vals[j]-mean)*rstd*g[j] + b[j]);
}

// ================= LayerNorm rows (dim=1024): optional fp32 out, optional bf16 out =================
__global__ __launch_bounds__(256) void ln_rows2(
    const float* __restrict__ in, const float* __restrict__ g,
    const float* __restrict__ b, const float* __restrict__ pos,
    float* __restrict__ outf, ushort4* __restrict__ outb) {
  long t = blockIdx.x;
  int tid = threadIdx.x;
  float4 v = ((const float4*)(in + t*DIMD))[tid];
  float s  = v.x+v.y+v.z+v.w;
  float s2 = v.x*v.x+v.y*v.y+v.z*v.z+v.w*v.w;
  __shared__ float rs[256], rq[256];
  rs[tid]=s; rq[tid]=s2; __syncthreads();
  for (int st = 128; st > 0; st >>= 1) {
    if (tid < st) { rs[tid]+=rs[tid+st]; rq[tid]+=rq[tid+st]; }
    __syncthreads();
  }
  float mean = rs[0]*(1.f/1024.f);
  float var  = rq[0]*(1.f/1024.f) - mean*mean;
  float rstd = rsqrtf(var + LN_EPS);
  float4 gg = ((const float4*)g)[tid];
  float4 bb = ((const float4*)b)[tid];
  float4 o;
  o.x = (v.x-mean)*rstd*gg.x + bb.x;
  o.y = (v.y-mean)*rstd*gg.y + bb.y;
  o.z = (v.z-mean)*rstd*gg.z + bb.z;
  o.w = (v.w-mean)*rstd*gg.w + bb.w;
  if (pos) {
    float4 pp = ((const float4*)(pos + (long)(t % NTOK)*DIMD))[tid];
    o.x += pp.x; o.y += pp.y; o.z += pp.z; o.w += pp.w;
  }
  if (outf) ((float4*)(outf + t*DIMD))[tid] = o;
  if (outb) {
    ushort4 u;
    u.x = bfbits(o.x); u.y = bfbits(o.y); u.z = bfbits(o.z); u.w = bfbits(o.w);
    outb[t*256 + tid] = u;
  }
}

// ================= cast + transpose weights: fp32 [R][C] -> bf16 [C][R] =================
__global__ void castT(const float* __restrict__ src, bf16* __restrict__ dst, int R, int C) {
  __shared__ float t[32][33];
  int rb = blockIdx.y*32, cb = blockIdx.x*32;
  int tx = threadIdx.x, ty = threadIdx.y;  // (32,8)
  for (int i = ty; i < 32; i += 8)
    if (rb+i < R && cb+tx < C) t[i][tx] = src[(long)(rb+i)*C + cb+tx];
  __syncthreads();
  for (int i = ty; i < 32; i += 8)
    if (cb+i < C && rb+tx < R) dst[(long)(cb+i)*R + rb+tx] = __float2bfloat16(t[tx][i]);
}

// ================= natural cast fp32 -> bf16 (elementwise, float4) =================
__global__ __launch_bounds__(256) void castN(
    const float* __restrict__ src, ushort4* __restrict__ dst) {
  int i = blockIdx.x*256 + threadIdx.x;
  float4 v = ((const float4*)src)[i];
  ushort4 u;
  u.x = bfbits(v.x); u.y = bfbits(v.y); u.z = bfbits(v.z); u.w = bfbits(v.w);
  dst[i] = u;
}

// ================= mean over tokens -> bf16 =================
__global__ __launch_bounds__(256) void mean_tokens(
    const float* __restrict__ x, bf16* __restrict__ outb) {
  int b = blockIdx.x;
  int d = blockIdx.y*256 + threadIdx.x;
  const float* p = x + (long)b*NTOK*DIMD + d;
  float s = 0.f;
  #pragma unroll 4
  for (int n = 0; n < NTOK; n++) s += p[(long)n*DIMD];
  outb[(long)b*DIMD + d] = __float2bfloat16(s * (1.f/196.f));
}

extern "C" void kernel_launch(void* const* d_in, const int* in_sizes, int n_in,
                              void* d_out, int out_size, void* d_ws, size_t ws_size,
                              hipStream_t stream) {
  (void)in_sizes; (void)n_in; (void)out_size; (void)ws_size;
  const float* image = (const float*)d_in[0];
  const float* ln1_g = (const float*)d_in[1];
  const float* ln1_b = (const float*)d_in[2];
  const float* W_emb = (const float*)d_in[3];
  const float* b_emb = (const float*)d_in[4];
  const float* ln2_g = (const float*)d_in[5];
  const float* ln2_b = (const float*)d_in[6];
  const float* pos   = (const float*)d_in[7];
  const float* norm_g= (const float*)d_in[8];
  const float* norm_b= (const float*)d_in[9];
  const float* WV    = (const float*)d_in[10];
  const float* WK    = (const float*)d_in[11];
  const float* WQ    = (const float*)d_in[12];
  const float* lastW = (const float*)d_in[13];
  const float* lastb = (const float*)d_in[14];
  float* out = (float*)d_out;

  char* W = (char*)d_ws;
  float* x     = (float*)(W);                      // 51,380,224
  bf16*  xnb   = (bf16*) (W + 51380224);           // 25,690,112
  bf16*  xm    = (bf16*) (W + 77070336);           // 25.7MB in 51.6MB slab (alias Xp; overread zone)
  bf16*  Xp    = xm;
  // slabB: embed-phase xn (fp32 51.4 MB) OR layer-phase Gt+Apad
  float* xn    = (float*)(W + 128712704);
  bf16*  Gt    = (bf16*) (W + 128712704);          // 29,360,128
  bf16*  Apad  = (bf16*) (W + 167907328);          //  7,340,032
  bf16*  WembT = (bf16*) (W + 180092928);          //  1,572,864
  bf16*  WQb   = (bf16*) (W + 181665792);          //  2,097,152 (natural layout)
  bf16*  WKb   = (bf16*) (W + 183762944);          //  2,097,152 (natural layout)
  bf16*  WVt   = (bf16*) (W + 185860096);          //     32,768
  bf16*  lastWT= (bf16*) (W + 185892864);          //  2,097,152
  bf16*  meanxb= (bf16*) (W + 187990016);          //    131,072
  float* clsPart=(float*)(W + 188121088);          //  2,097,152
  bf16*  Mt    = (bf16*) (W + 190218240);          //  2,097,152 (M^T = WK @ WQ^T)

  dim3 blk(256);
  const float scale = 0.08838834764831845f;  // 128^-0.5
  const long ZR = 0;

  // weight casts
  castT<<<dim3(32, 24), dim3(32, 8), 0, stream>>>(W_emb, WembT, PD, DIMD);
  castN<<<1024, blk, 0, stream>>>(WQ, (ushort4*)WQb);
  castN<<<1024, blk, 0, stream>>>(WK, (ushort4*)WKb);
  castT<<<dim3(4, 4),  dim3(32, 8), 0, stream>>>(WV, WVt, HD, HD);
  castT<<<dim3(32, 32), dim3(32, 8), 0, stream>>>(lastW, lastWT, DIMD, 1000);
  // Mt[j][i] = sum_k WK[j][k]*WQ[i][k]  (= (WQ @ WK^T)^T)
  gemm_mfma<<<dim3(8, 8, 1), blk, 0, stream>>>(
      WKb, DIMD, ZR, WQb, DIMD, ZR, DIMD, 1,
      nullptr, Mt, DIMD, ZR, nullptr, nullptr, ZR, 1.f, DIMD, DIMD);

  // patch embed
  patchify_ln<<<TOKENS, blk, 0, stream>>>(image, ln1_g, ln1_b, Xp);
  gemm_mfma<<<dim3(8, 98, 1), blk, 0, stream>>>(
      Xp, PD, ZR, WembT, PD, ZR, PD, 0,
      xn, nullptr, DIMD, ZR, b_emb, nullptr, ZR, 1.f, TOKENS, DIMD);
  ln_rows2<<<TOKENS, blk, 0, stream>>>(xn, ln2_g, ln2_b, pos, x, nullptr);

  for (int l = 0; l < DEPTH; l++) {
    // xnb = bf16(LN(x))
    ln_rows2<<<TOKENS, blk, 0, stream>>>(x, norm_g, norm_b, nullptr, nullptr, (ushort4*)xnb);
    // xm = xnb @ M
    gemm_mfma<<<dim3(8, 98, 1), blk, 0, stream>>>(
        xnb, DIMD, ZR, Mt, DIMD, ZR, DIMD, 1,
        nullptr, xm, DIMD, ZR, nullptr, nullptr, ZR, 1.f, TOKENS, DIMD);
    // Apad = softmax(xm @ xnb^T * scale), fused, pads zeroed
    gemm_qs<<<dim3(1, 4, BATCH), blk, 0, stream>>>(xm, xnb, Apad, scale);
    // Gt[b][dim][tok] = WV^T @ xn^T  (direct transposed layout, pad cols zeroed)
    gemm_v<<<dim3(2, HEADS, BATCH), blk, 0, stream>>>(WVt, xnb, Gt);
    // x = Apad @ G + xnb (bf16 residual)
    gemm_mfma<<<dim3(8, 2, BATCH), blk, 0, stream>>>(
        Apad, APAD_C, (long)APAD_R*APAD_C, Gt, APAD_C, (long)DIMD*APAD_C, APAD_C, 0,
        x, nullptr, DIMD, (long)NTOK*DIMD, nullptr, xnb, (long)NTOK*DIMD, 1.f, NTOK, DIMD);
  }

  // classifier
  mean_tokens<<<dim3(BATCH, 4), blk, 0, stream>>>(x, meanxb);
  gemm_cls<<<dim3(8, 8), blk, 0, stream>>>(meanxb, lastWT, clsPart);
  cls_reduce<<<250, blk, 0, stream>>>(clsPart, lastb, out);
}